// Round 1
// baseline (558.612 us; speedup 1.0000x reference)
//
#include <hip/hip_runtime.h>
#include <hip/hip_bf16.h>
#include <cmath>

#define D_MODEL 768
#define NHEAD 12
#define HD 64
#define L_SEQ 2048
#define WIN 128
#define QKV_N (3 * D_MODEL)

// ---------------------------------------------------------------------------
// Generic fp32 GEMM with bias: C[M][N] = A[M][K] @ B[K][N] + bias[N]
// 64x64 tile, BK=16, 256 threads, 4x4 micro-tile per thread.
// ---------------------------------------------------------------------------
#define TILE 64
#define BK 16

__global__ __launch_bounds__(256) void gemm_bias_kernel(
    const float* __restrict__ A, const float* __restrict__ B,
    const float* __restrict__ bias, float* __restrict__ C,
    int M, int N, int K) {
  __shared__ float As[BK][TILE + 1];  // [k][m], +1 pad to spread banks
  __shared__ float Bs[BK][TILE];      // [k][n], float4-aligned stores

  const int tid = threadIdx.x;
  const int row0 = blockIdx.y * TILE;
  const int col0 = blockIdx.x * TILE;
  const int tx = tid & 15;   // 0..15 -> 4 cols each
  const int ty = tid >> 4;   // 0..15 -> 4 rows each

  float acc[4][4] = {};

  for (int k0 = 0; k0 < K; k0 += BK) {
    // Load A tile 64x16 (one float4 per thread)
    {
      const int m = tid >> 2;            // 0..63
      const int k4 = (tid & 3) << 2;     // 0,4,8,12
      const float4 a = *reinterpret_cast<const float4*>(
          &A[(size_t)(row0 + m) * K + k0 + k4]);
      As[k4 + 0][m] = a.x;
      As[k4 + 1][m] = a.y;
      As[k4 + 2][m] = a.z;
      As[k4 + 3][m] = a.w;
    }
    // Load B tile 16x64 (one float4 per thread)
    {
      const int kk = tid >> 4;           // 0..15
      const int n4 = (tid & 15) << 2;    // 0..60
      const float4 b = *reinterpret_cast<const float4*>(
          &B[(size_t)(k0 + kk) * N + col0 + n4]);
      *reinterpret_cast<float4*>(&Bs[kk][n4]) = b;
    }
    __syncthreads();

#pragma unroll
    for (int kk = 0; kk < BK; ++kk) {
      float a[4], b[4];
#pragma unroll
      for (int i = 0; i < 4; ++i) a[i] = As[kk][ty * 4 + i];
#pragma unroll
      for (int j = 0; j < 4; ++j) b[j] = Bs[kk][tx * 4 + j];
#pragma unroll
      for (int i = 0; i < 4; ++i)
#pragma unroll
        for (int j = 0; j < 4; ++j) acc[i][j] += a[i] * b[j];
    }
    __syncthreads();
  }

#pragma unroll
  for (int i = 0; i < 4; ++i) {
    const int r = row0 + ty * 4 + i;
#pragma unroll
    for (int j = 0; j < 4; ++j) {
      const int c = col0 + tx * 4 + j;
      C[(size_t)r * N + c] = acc[i][j] + bias[c];
    }
  }
}

// ---------------------------------------------------------------------------
// RoPE + split: qkv[L][2304] -> q,k,v each [H][L][64]; RoPE applied to q,k.
// rotate-half: out[:32] = x1*cos - x2*sin ; out[32:] = x1*sin + x2*cos
// grid (L, H), 64 threads (one per d)
// ---------------------------------------------------------------------------
__global__ __launch_bounds__(64) void rope_split_kernel(
    const float* __restrict__ qkv, float* __restrict__ q,
    float* __restrict__ k, float* __restrict__ v) {
  const int l = blockIdx.x;
  const int h = blockIdx.y;
  const int d = threadIdx.x;  // 0..63
  const int i = d & 31;       // freq index

  const float inv = (float)(1.0 / pow(10000.0, (double)(2 * i) / 64.0));
  const float ang = (float)l * inv;
  const float c = cosf(ang);
  const float s = sinf(ang);

  const size_t base = (size_t)l * QKV_N + h * HD;
  const size_t obase = ((size_t)h * L_SEQ + l) * HD + d;

  // q
  {
    const float x = qkv[base + d];
    const float xp = qkv[base + (d ^ 32)];
    q[obase] = (d < 32) ? (x * c - xp * s) : (xp * s + x * c);
  }
  // k
  {
    const float x = qkv[base + D_MODEL + d];
    const float xp = qkv[base + D_MODEL + (d ^ 32)];
    k[obase] = (d < 32) ? (x * c - xp * s) : (xp * s + x * c);
  }
  // v (plain copy)
  v[obase] = qkv[base + 2 * D_MODEL + d];
}

// ---------------------------------------------------------------------------
// Sliding-window attention: one block (128 threads) per (l, h).
// K window staged in LDS (padded). Block softmax. V read coalesced from L2.
// joined[L][768]
// ---------------------------------------------------------------------------
__global__ __launch_bounds__(128) void win_attn_kernel(
    const float* __restrict__ q, const float* __restrict__ k,
    const float* __restrict__ v, const int* __restrict__ mask,
    float* __restrict__ joined) {
  const int l = blockIdx.x;
  const int h = blockIdx.y;
  const int tid = threadIdx.x;
  const float scale = 0.036084391824351615f;  // 1/sqrt(768)

  __shared__ float qv[HD];
  __shared__ float kS[WIN][HD + 1];
  __shared__ float sc[WIN];
  __shared__ float red[WIN];

  const float* kh = k + (size_t)h * L_SEQ * HD;
  const float* vh = v + (size_t)h * L_SEQ * HD;

  if (tid < HD) qv[tid] = q[((size_t)h * L_SEQ + l) * HD + tid];

  // stage K window (mostly contiguous rows l-64 .. l+63, clipped)
#pragma unroll 4
  for (int j = 0; j < 64; ++j) {
    const int linear = j * 128 + tid;
    const int w = linear >> 6;
    const int d = linear & 63;
    const int raw = l + w - WIN / 2;
    const int idx = min(max(raw, 0), L_SEQ - 1);
    kS[w][d] = kh[(size_t)idx * HD + d];
  }
  __syncthreads();

  // scores
  const int w = tid;
  const int raw = l + w - WIN / 2;
  const int idx = min(max(raw, 0), L_SEQ - 1);
  const bool valid = (raw >= 0) && (raw < L_SEQ) && (mask[idx] != 0);
  float s = -INFINITY;
  if (valid) {
    float acc = 0.f;
#pragma unroll
    for (int d = 0; d < HD; ++d) acc += kS[w][d] * qv[d];
    s = acc * scale;
  }
  sc[tid] = s;
  red[tid] = s;
  __syncthreads();

  // max reduce
  for (int off = 64; off > 0; off >>= 1) {
    if (tid < off) red[tid] = fmaxf(red[tid], red[tid + off]);
    __syncthreads();
  }
  const float mx = red[0];
  __syncthreads();

  const float e = expf(s - mx);  // -inf -> 0
  sc[tid] = e;
  red[tid] = e;
  __syncthreads();

  // sum reduce
  for (int off = 64; off > 0; off >>= 1) {
    if (tid < off) red[tid] += red[tid + off];
    __syncthreads();
  }
  const float total = red[0];
  __syncthreads();

  // output: thread d accumulates over window
  if (tid < HD) {
    float acc = 0.f;
#pragma unroll 4
    for (int w2 = 0; w2 < WIN; ++w2) {
      const int raw2 = l + w2 - WIN / 2;
      const int idx2 = min(max(raw2, 0), L_SEQ - 1);
      acc += sc[w2] * vh[(size_t)idx2 * HD + tid];
    }
    joined[(size_t)l * D_MODEL + h * HD + tid] = acc / total;
  }
}

// ---------------------------------------------------------------------------
// CLS global attention for position 0: one block (256 threads) per head.
// Overwrites joined[0][h*64 .. h*64+63].
// ---------------------------------------------------------------------------
__global__ __launch_bounds__(256) void cls_attn_kernel(
    const float* __restrict__ q, const float* __restrict__ k,
    const float* __restrict__ v, const int* __restrict__ mask,
    float* __restrict__ joined) {
  const int h = blockIdx.x;
  const int tid = threadIdx.x;
  const float scale = 0.036084391824351615f;

  __shared__ float q0[HD];
  __shared__ float sc[L_SEQ];
  __shared__ float red[256];

  const float* kh = k + (size_t)h * L_SEQ * HD;
  const float* vh = v + (size_t)h * L_SEQ * HD;

  if (tid < HD) q0[tid] = q[(size_t)h * L_SEQ * HD + tid];
  __syncthreads();

  for (int l = tid; l < L_SEQ; l += 256) {
    float s = 0.f;
#pragma unroll
    for (int d = 0; d < HD; ++d) s += kh[(size_t)l * HD + d] * q0[d];
    sc[l] = (mask[l] != 0) ? s * scale : -INFINITY;
  }
  __syncthreads();

  float m = -INFINITY;
  for (int l = tid; l < L_SEQ; l += 256) m = fmaxf(m, sc[l]);
  red[tid] = m;
  __syncthreads();
  for (int off = 128; off > 0; off >>= 1) {
    if (tid < off) red[tid] = fmaxf(red[tid], red[tid + off]);
    __syncthreads();
  }
  const float mx = red[0];
  __syncthreads();

  float ssum = 0.f;
  for (int l = tid; l < L_SEQ; l += 256) {
    const float e = expf(sc[l] - mx);
    sc[l] = e;
    ssum += e;
  }
  red[tid] = ssum;
  __syncthreads();
  for (int off = 128; off > 0; off >>= 1) {
    if (tid < off) red[tid] += red[tid + off];
    __syncthreads();
  }
  const float total = red[0];
  __syncthreads();

  if (tid < HD) {
    float acc = 0.f;
    for (int l = 0; l < L_SEQ; ++l) acc += sc[l] * vh[(size_t)l * HD + tid];
    joined[(size_t)h * HD + tid] = acc / total;
  }
}

// ---------------------------------------------------------------------------
extern "C" void kernel_launch(void* const* d_in, const int* in_sizes, int n_in,
                              void* d_out, int out_size, void* d_ws,
                              size_t ws_size, hipStream_t stream) {
  const float* emb   = (const float*)d_in[0];  // [1][2048][768]
  const int*   mask  = (const int*)d_in[1];    // [1][2048]
  const float* W_qkv = (const float*)d_in[2];  // [768][2304]
  const float* b_qkv = (const float*)d_in[3];  // [2304]
  const float* W_o   = (const float*)d_in[4];  // [768][768]
  const float* b_o   = (const float*)d_in[5];  // [768]
  float* out = (float*)d_out;                  // [2048][768]

  float* ws = (float*)d_ws;
  float* qkv = ws;                                   // 2048*2304
  float* qbuf = qkv + (size_t)L_SEQ * QKV_N;         // 12*2048*64
  float* kbuf = qbuf + (size_t)NHEAD * L_SEQ * HD;
  float* vbuf = kbuf + (size_t)NHEAD * L_SEQ * HD;
  float* joined = qkv;  // alias: qkv dead after rope_split

  // 1. QKV GEMM
  gemm_bias_kernel<<<dim3(QKV_N / TILE, L_SEQ / TILE), 256, 0, stream>>>(
      emb, W_qkv, b_qkv, qkv, L_SEQ, QKV_N, D_MODEL);

  // 2. RoPE + head split
  rope_split_kernel<<<dim3(L_SEQ, NHEAD), 64, 0, stream>>>(qkv, qbuf, kbuf,
                                                           vbuf);

  // 3. Window attention
  win_attn_kernel<<<dim3(L_SEQ, NHEAD), 128, 0, stream>>>(qbuf, kbuf, vbuf,
                                                          mask, joined);

  // 4. CLS attention (overwrites row 0)
  cls_attn_kernel<<<NHEAD, 256, 0, stream>>>(qbuf, kbuf, vbuf, mask, joined);

  // 5. Output GEMM
  gemm_bias_kernel<<<dim3(D_MODEL / TILE, L_SEQ / TILE), 256, 0, stream>>>(
      joined, W_o, b_o, out, L_SEQ, D_MODEL, D_MODEL);
}

// Round 3
// 524.519 us; speedup vs baseline: 1.0650x; 1.0650x over previous
//
#include <hip/hip_runtime.h>
#include <hip/hip_bf16.h>
#include <cmath>

#define D_MODEL 768
#define NHEAD 12
#define HD 64
#define L_SEQ 2048
#define WIN 128
#define QKV_N (3 * D_MODEL)
#define BK 16

// ---------------------------------------------------------------------------
// fp32 GEMM with bias: C[M][N] = A[M][K] @ B[K][N] + bias[N]
// Tile (64*MH) x (64*NH), BK=16, 256 threads, micro-tile 4x4 quads.
// ---------------------------------------------------------------------------
template <int MH, int NH>
__global__ __launch_bounds__(256) void gemm_bias_kernel(
    const float* __restrict__ A, const float* __restrict__ B,
    const float* __restrict__ bias, float* __restrict__ C,
    int M, int N, int K) {
  constexpr int LDA = 64 * MH + 4;  // +4 floats: conflict-free scatter, keeps 16B align
  constexpr int LDB = 64 * NH;
  __shared__ float As[BK * LDA];  // [k][m]
  __shared__ float Bs[BK * LDB];  // [k][n]

  const int tid = threadIdx.x;
  const int row0 = blockIdx.y * (64 * MH);
  const int col0 = blockIdx.x * (64 * NH);
  const int tx = tid & 15;
  const int ty = tid >> 4;

  float acc[4 * MH][4 * NH] = {};

  for (int k0 = 0; k0 < K; k0 += BK) {
    // A tile: 64*MH rows x 16 k, one float4 per thread per mh, scatter to [k][m]
    {
      const int m_local = tid >> 2;        // 0..63
      const int kq = (tid & 3) << 2;       // 0,4,8,12
#pragma unroll
      for (int mh = 0; mh < MH; ++mh) {
        const int m = mh * 64 + m_local;
        const float4 a4 = *reinterpret_cast<const float4*>(
            &A[(size_t)(row0 + m) * K + k0 + kq]);
        As[(kq + 0) * LDA + m] = a4.x;
        As[(kq + 1) * LDA + m] = a4.y;
        As[(kq + 2) * LDA + m] = a4.z;
        As[(kq + 3) * LDA + m] = a4.w;
      }
    }
    // B tile: 16 x 64*NH
    {
      const int kk = tid >> 4;
#pragma unroll
      for (int nh = 0; nh < NH; ++nh) {
        const int n4 = nh * 64 + tx * 4;
        *reinterpret_cast<float4*>(&Bs[kk * LDB + n4]) =
            *reinterpret_cast<const float4*>(&B[(size_t)(k0 + kk) * N + col0 + n4]);
      }
    }
    __syncthreads();

#pragma unroll
    for (int kk = 0; kk < BK; ++kk) {
      float a[MH][4], b[NH][4];
#pragma unroll
      for (int mh = 0; mh < MH; ++mh)
        *reinterpret_cast<float4*>(a[mh]) =
            *reinterpret_cast<const float4*>(&As[kk * LDA + mh * 64 + ty * 4]);
#pragma unroll
      for (int nh = 0; nh < NH; ++nh)
        *reinterpret_cast<float4*>(b[nh]) =
            *reinterpret_cast<const float4*>(&Bs[kk * LDB + nh * 64 + tx * 4]);
#pragma unroll
      for (int mh = 0; mh < MH; ++mh)
#pragma unroll
        for (int i = 0; i < 4; ++i)
#pragma unroll
          for (int nh = 0; nh < NH; ++nh)
#pragma unroll
            for (int j = 0; j < 4; ++j)
              acc[mh * 4 + i][nh * 4 + j] += a[mh][i] * b[nh][j];
    }
    __syncthreads();
  }

#pragma unroll
  for (int mh = 0; mh < MH; ++mh)
#pragma unroll
    for (int i = 0; i < 4; ++i) {
      const int r = row0 + mh * 64 + ty * 4 + i;
#pragma unroll
      for (int nh = 0; nh < NH; ++nh) {
        const int c = col0 + nh * 64 + tx * 4;
        const float4 b4 = *reinterpret_cast<const float4*>(&bias[c]);
        float4 o;
        o.x = acc[mh * 4 + i][nh * 4 + 0] + b4.x;
        o.y = acc[mh * 4 + i][nh * 4 + 1] + b4.y;
        o.z = acc[mh * 4 + i][nh * 4 + 2] + b4.z;
        o.w = acc[mh * 4 + i][nh * 4 + 3] + b4.w;
        *reinterpret_cast<float4*>(&C[(size_t)r * N + c]) = o;
      }
    }
}

// ---------------------------------------------------------------------------
// RoPE + split (unchanged from R1 — passed, cheap).
// ---------------------------------------------------------------------------
__global__ __launch_bounds__(64) void rope_split_kernel(
    const float* __restrict__ qkv, float* __restrict__ q,
    float* __restrict__ k, float* __restrict__ v) {
  const int l = blockIdx.x;
  const int h = blockIdx.y;
  const int d = threadIdx.x;
  const int i = d & 31;

  const float inv = (float)(1.0 / pow(10000.0, (double)(2 * i) / 64.0));
  const float ang = (float)l * inv;
  const float c = cosf(ang);
  const float s = sinf(ang);

  const size_t base = (size_t)l * QKV_N + h * HD;
  const size_t obase = ((size_t)h * L_SEQ + l) * HD + d;

  {
    const float x = qkv[base + d];
    const float xp = qkv[base + (d ^ 32)];
    q[obase] = (d < 32) ? (x * c - xp * s) : (xp * s + x * c);
  }
  {
    const float x = qkv[base + D_MODEL + d];
    const float xp = qkv[base + D_MODEL + (d ^ 32)];
    k[obase] = (d < 32) ? (x * c - xp * s) : (xp * s + x * c);
  }
  v[obase] = qkv[base + 2 * D_MODEL + d];
}

// ---------------------------------------------------------------------------
// Window attention v2: block = (32 q-rows, 1 head), 256 threads.
// K window (160 slots x 64) staged once in XOR-swizzled LDS; after scores the
// same buffer is re-staged with V. Softmax fully via 8-lane shuffles.
// ---------------------------------------------------------------------------
#define TL 32
#define NSLOT (TL + WIN)  // 160

__global__ __launch_bounds__(256) void win_attn_kernel(
    const float* __restrict__ q, const float* __restrict__ k,
    const float* __restrict__ v, const int* __restrict__ mask,
    float* __restrict__ joined) {
  const int l0 = blockIdx.x * TL;
  const int h = blockIdx.y;
  const int tid = threadIdx.x;
  const float scale = 0.036084391824351615f;  // 1/sqrt(768)

  __shared__ float kvS[NSLOT * HD];      // swizzled: chunk d4 stored at d4 ^ (slot&7)
  __shared__ float sS[TL * (WIN + 4)];   // normalized probs, +4 pad
  __shared__ float vbias[NSLOT];         // 0 or -inf per slot

  const float* kh = k + (size_t)h * L_SEQ * HD;
  const float* vh = v + (size_t)h * L_SEQ * HD;
  const float* qh = q + (size_t)h * L_SEQ * HD;

  // ---- stage K (swizzled) ----
  for (int c = tid; c < NSLOT * 16; c += 256) {
    const int slot = c >> 4;
    const int d4 = c & 15;
    const int raw = l0 + slot - WIN / 2;
    const int idx = min(max(raw, 0), L_SEQ - 1);
    const float4 k4 = *reinterpret_cast<const float4*>(&kh[(size_t)idx * HD + d4 * 4]);
    *reinterpret_cast<float4*>(&kvS[slot * HD + ((d4 ^ (slot & 7)) << 2)]) = k4;
  }
  if (tid < NSLOT) {
    const int raw = l0 + tid - WIN / 2;
    const int idx = min(max(raw, 0), L_SEQ - 1);
    const bool valid = (raw >= 0) && (raw < L_SEQ) && (mask[idx] != 0);
    vbias[tid] = valid ? 0.f : -INFINITY;
  }
  __syncthreads();

  // ---- scores: thread (r = tid>>3, wg = tid&7) owns 16 w values ----
  const int r = tid >> 3;
  const int wg = tid & 7;
  int koff[16], kx4[16];
#pragma unroll
  for (int wi = 0; wi < 16; ++wi) {
    const int slot = r + wg * 16 + wi;
    koff[wi] = slot * HD;
    kx4[wi] = (slot & 7) << 2;
  }
  float acc[16] = {};
#pragma unroll
  for (int d4 = 0; d4 < 16; ++d4) {
    const float4 q4 = *reinterpret_cast<const float4*>(
        &qh[(size_t)(l0 + r) * HD + d4 * 4]);
    const int d44 = d4 << 2;
#pragma unroll
    for (int wi = 0; wi < 16; ++wi) {
      const float4 k4 =
          *reinterpret_cast<const float4*>(&kvS[koff[wi] + (d44 ^ kx4[wi])]);
      acc[wi] += q4.x * k4.x + q4.y * k4.y + q4.z * k4.z + q4.w * k4.w;
    }
  }
  float pv[16];
  float mloc = -INFINITY;
#pragma unroll
  for (int wi = 0; wi < 16; ++wi) {
    pv[wi] = acc[wi] * scale + vbias[r + wg * 16 + wi];
    mloc = fmaxf(mloc, pv[wi]);
  }
#pragma unroll
  for (int m = 1; m < 8; m <<= 1) mloc = fmaxf(mloc, __shfl_xor(mloc, m));
  float ssum = 0.f;
#pragma unroll
  for (int wi = 0; wi < 16; ++wi) {
    pv[wi] = __expf(pv[wi] - mloc);
    ssum += pv[wi];
  }
#pragma unroll
  for (int m = 1; m < 8; m <<= 1) ssum += __shfl_xor(ssum, m);
  const float rcp = 1.0f / ssum;
#pragma unroll
  for (int wi = 0; wi < 16; ++wi)
    sS[r * (WIN + 4) + wg * 16 + wi] = pv[wi] * rcp;
  __syncthreads();

  // ---- re-stage with V (same swizzle) ----
  for (int c = tid; c < NSLOT * 16; c += 256) {
    const int slot = c >> 4;
    const int d4 = c & 15;
    const int raw = l0 + slot - WIN / 2;
    const int idx = min(max(raw, 0), L_SEQ - 1);
    const float4 v4 = *reinterpret_cast<const float4*>(&vh[(size_t)idx * HD + d4 * 4]);
    *reinterpret_cast<float4*>(&kvS[slot * HD + ((d4 ^ (slot & 7)) << 2)]) = v4;
  }
  __syncthreads();

  // ---- PV: thread (r = tid>>3, dg = tid&7) owns 8 d values ----
  const int dg = tid & 7;
  float o[8] = {};
#pragma unroll 4
  for (int w = 0; w < WIN; ++w) {
    const float p = sS[r * (WIN + 4) + w];
    const int slot = r + w;
    const int base = slot * HD;
    const int x4 = (slot & 7) << 2;
    const float4 vA =
        *reinterpret_cast<const float4*>(&kvS[base + ((dg << 3) ^ x4)]);
    const float4 vB =
        *reinterpret_cast<const float4*>(&kvS[base + (((dg << 3) + 4) ^ x4)]);
    o[0] += p * vA.x; o[1] += p * vA.y; o[2] += p * vA.z; o[3] += p * vA.w;
    o[4] += p * vB.x; o[5] += p * vB.y; o[6] += p * vB.z; o[7] += p * vB.w;
  }
  float4 o0 = {o[0], o[1], o[2], o[3]};
  float4 o1 = {o[4], o[5], o[6], o[7]};
  float* dst = &joined[(size_t)(l0 + r) * D_MODEL + h * HD + dg * 8];
  *reinterpret_cast<float4*>(dst) = o0;
  *reinterpret_cast<float4*>(dst + 4) = o1;
}

// ---------------------------------------------------------------------------
// CLS attention v2: one block (256 threads) per head, fully parallel.
// ---------------------------------------------------------------------------
__global__ __launch_bounds__(256) void cls_attn_kernel(
    const float* __restrict__ q, const float* __restrict__ k,
    const float* __restrict__ v, const int* __restrict__ mask,
    float* __restrict__ joined) {
  const int h = blockIdx.x;
  const int tid = threadIdx.x;
  const float scale = 0.036084391824351615f;

  __shared__ float scS[L_SEQ];
  __shared__ float red[256];
  __shared__ float part[4][HD];

  const float* kh = k + (size_t)h * L_SEQ * HD;
  const float* vh = v + (size_t)h * L_SEQ * HD;

  // scores: 16 threads per row (dq = tid&15 covers d), 16 rows in flight
  const int lq = tid >> 4;   // 0..15
  const int dq = tid & 15;   // 0..15
  const float4 q4 = *reinterpret_cast<const float4*>(
      &q[(size_t)h * L_SEQ * HD + dq * 4]);
#pragma unroll 4
  for (int it = 0; it < L_SEQ / 16; ++it) {
    const int l = it * 16 + lq;
    const float4 k4 = *reinterpret_cast<const float4*>(&kh[(size_t)l * HD + dq * 4]);
    float p = q4.x * k4.x + q4.y * k4.y + q4.z * k4.z + q4.w * k4.w;
#pragma unroll
    for (int m = 1; m < 16; m <<= 1) p += __shfl_xor(p, m);
    if (dq == 0) scS[l] = (mask[l] != 0) ? p * scale : -INFINITY;
  }
  __syncthreads();

  // block max
  float mx = -INFINITY;
#pragma unroll
  for (int i = 0; i < L_SEQ / 256; ++i) mx = fmaxf(mx, scS[tid + i * 256]);
  red[tid] = mx;
  __syncthreads();
  for (int off = 128; off > 0; off >>= 1) {
    if (tid < off) red[tid] = fmaxf(red[tid], red[tid + off]);
    __syncthreads();
  }
  mx = red[0];
  __syncthreads();

  // exp + sum
  float lsum = 0.f;
#pragma unroll
  for (int i = 0; i < L_SEQ / 256; ++i) {
    const int l = tid + i * 256;
    const float e = __expf(scS[l] - mx);
    scS[l] = e;
    lsum += e;
  }
  red[tid] = lsum;
  __syncthreads();
  for (int off = 128; off > 0; off >>= 1) {
    if (tid < off) red[tid] += red[tid + off];
    __syncthreads();
  }
  const float total = red[0];
  __syncthreads();

  // PV: 4-way l-split, 64 d-lanes each
  const int lg = tid >> 6;  // 0..3
  const int d = tid & 63;
  float acc = 0.f;
  for (int l = lg; l < L_SEQ; l += 4) acc += scS[l] * vh[(size_t)l * HD + d];
  part[lg][d] = acc;
  __syncthreads();
  if (tid < HD) {
    const float o = (part[0][tid] + part[1][tid] + part[2][tid] + part[3][tid]) / total;
    joined[(size_t)h * HD + tid] = o;
  }
}

// ---------------------------------------------------------------------------
extern "C" void kernel_launch(void* const* d_in, const int* in_sizes, int n_in,
                              void* d_out, int out_size, void* d_ws,
                              size_t ws_size, hipStream_t stream) {
  const float* emb   = (const float*)d_in[0];
  const int*   mask  = (const int*)d_in[1];
  const float* W_qkv = (const float*)d_in[2];
  const float* b_qkv = (const float*)d_in[3];
  const float* W_o   = (const float*)d_in[4];
  const float* b_o   = (const float*)d_in[5];
  float* out = (float*)d_out;

  float* ws = (float*)d_ws;
  float* qkv = ws;                                   // 2048*2304
  float* qbuf = qkv + (size_t)L_SEQ * QKV_N;
  float* kbuf = qbuf + (size_t)NHEAD * L_SEQ * HD;
  float* vbuf = kbuf + (size_t)NHEAD * L_SEQ * HD;
  float* joined = qkv;  // qkv dead after rope_split

  gemm_bias_kernel<2, 2><<<dim3(QKV_N / 128, L_SEQ / 128), 256, 0, stream>>>(
      emb, W_qkv, b_qkv, qkv, L_SEQ, QKV_N, D_MODEL);

  rope_split_kernel<<<dim3(L_SEQ, NHEAD), 64, 0, stream>>>(qkv, qbuf, kbuf, vbuf);

  win_attn_kernel<<<dim3(L_SEQ / TL, NHEAD), 256, 0, stream>>>(qbuf, kbuf, vbuf,
                                                               mask, joined);

  cls_attn_kernel<<<NHEAD, 256, 0, stream>>>(qbuf, kbuf, vbuf, mask, joined);

  gemm_bias_kernel<2, 1><<<dim3(D_MODEL / 64, L_SEQ / 128), 256, 0, stream>>>(
      joined, W_o, b_o, out, L_SEQ, D_MODEL, D_MODEL);
}

// Round 4
// 360.383 us; speedup vs baseline: 1.5501x; 1.4554x over previous
//
#include <hip/hip_runtime.h>
#include <hip/hip_bf16.h>
#include <cmath>

#define D_MODEL 768
#define NHEAD 12
#define HD 64
#define L_SEQ 2048
#define WIN 128
#define QKV_N (3 * D_MODEL)
#define BK 16

// ---------------------------------------------------------------------------
// fp32 GEMM with bias: C[M][N] = A[M][K] @ B[K][N] + bias[N]
// Tile (64*MH) x (64*NH), BK=16, 256 threads, micro-tile 4x4 quads.
// ---------------------------------------------------------------------------
template <int MH, int NH>
__global__ __launch_bounds__(256) void gemm_bias_kernel(
    const float* __restrict__ A, const float* __restrict__ B,
    const float* __restrict__ bias, float* __restrict__ C,
    int M, int N, int K) {
  constexpr int LDA = 64 * MH + 4;
  constexpr int LDB = 64 * NH;
  __shared__ float As[BK * LDA];  // [k][m]
  __shared__ float Bs[BK * LDB];  // [k][n]

  const int tid = threadIdx.x;
  const int row0 = blockIdx.y * (64 * MH);
  const int col0 = blockIdx.x * (64 * NH);
  const int tx = tid & 15;
  const int ty = tid >> 4;

  float acc[4 * MH][4 * NH] = {};

  for (int k0 = 0; k0 < K; k0 += BK) {
    {
      const int m_local = tid >> 2;
      const int kq = (tid & 3) << 2;
#pragma unroll
      for (int mh = 0; mh < MH; ++mh) {
        const int m = mh * 64 + m_local;
        const float4 a4 = *reinterpret_cast<const float4*>(
            &A[(size_t)(row0 + m) * K + k0 + kq]);
        As[(kq + 0) * LDA + m] = a4.x;
        As[(kq + 1) * LDA + m] = a4.y;
        As[(kq + 2) * LDA + m] = a4.z;
        As[(kq + 3) * LDA + m] = a4.w;
      }
    }
    {
      const int kk = tid >> 4;
#pragma unroll
      for (int nh = 0; nh < NH; ++nh) {
        const int n4 = nh * 64 + tx * 4;
        *reinterpret_cast<float4*>(&Bs[kk * LDB + n4]) =
            *reinterpret_cast<const float4*>(&B[(size_t)(k0 + kk) * N + col0 + n4]);
      }
    }
    __syncthreads();

#pragma unroll
    for (int kk = 0; kk < BK; ++kk) {
      float a[MH][4], b[NH][4];
#pragma unroll
      for (int mh = 0; mh < MH; ++mh)
        *reinterpret_cast<float4*>(a[mh]) =
            *reinterpret_cast<const float4*>(&As[kk * LDA + mh * 64 + ty * 4]);
#pragma unroll
      for (int nh = 0; nh < NH; ++nh)
        *reinterpret_cast<float4*>(b[nh]) =
            *reinterpret_cast<const float4*>(&Bs[kk * LDB + nh * 64 + tx * 4]);
#pragma unroll
      for (int mh = 0; mh < MH; ++mh)
#pragma unroll
        for (int i = 0; i < 4; ++i)
#pragma unroll
          for (int nh = 0; nh < NH; ++nh)
#pragma unroll
            for (int j = 0; j < 4; ++j)
              acc[mh * 4 + i][nh * 4 + j] += a[mh][i] * b[nh][j];
    }
    __syncthreads();
  }

#pragma unroll
  for (int mh = 0; mh < MH; ++mh)
#pragma unroll
    for (int i = 0; i < 4; ++i) {
      const int r = row0 + mh * 64 + ty * 4 + i;
#pragma unroll
      for (int nh = 0; nh < NH; ++nh) {
        const int c = col0 + nh * 64 + tx * 4;
        const float4 b4 = *reinterpret_cast<const float4*>(&bias[c]);
        float4 o;
        o.x = acc[mh * 4 + i][nh * 4 + 0] + b4.x;
        o.y = acc[mh * 4 + i][nh * 4 + 1] + b4.y;
        o.z = acc[mh * 4 + i][nh * 4 + 2] + b4.z;
        o.w = acc[mh * 4 + i][nh * 4 + 3] + b4.w;
        *reinterpret_cast<float4*>(&C[(size_t)r * N + c]) = o;
      }
    }
}

// ---------------------------------------------------------------------------
// RoPE + split (unchanged).
// ---------------------------------------------------------------------------
__global__ __launch_bounds__(64) void rope_split_kernel(
    const float* __restrict__ qkv, float* __restrict__ q,
    float* __restrict__ k, float* __restrict__ v) {
  const int l = blockIdx.x;
  const int h = blockIdx.y;
  const int d = threadIdx.x;
  const int i = d & 31;

  const float inv = (float)(1.0 / pow(10000.0, (double)(2 * i) / 64.0));
  const float ang = (float)l * inv;
  const float c = cosf(ang);
  const float s = sinf(ang);

  const size_t base = (size_t)l * QKV_N + h * HD;
  const size_t obase = ((size_t)h * L_SEQ + l) * HD + d;

  {
    const float x = qkv[base + d];
    const float xp = qkv[base + (d ^ 32)];
    q[obase] = (d < 32) ? (x * c - xp * s) : (xp * s + x * c);
  }
  {
    const float x = qkv[base + D_MODEL + d];
    const float xp = qkv[base + D_MODEL + (d ^ 32)];
    k[obase] = (d < 32) ? (x * c - xp * s) : (xp * s + x * c);
  }
  v[obase] = qkv[base + 2 * D_MODEL + d];
}

// ---------------------------------------------------------------------------
// Window attention v2 (unchanged from R2/R3 run).
// ---------------------------------------------------------------------------
#define TL 32
#define NSLOT (TL + WIN)  // 160

__global__ __launch_bounds__(256) void win_attn_kernel(
    const float* __restrict__ q, const float* __restrict__ k,
    const float* __restrict__ v, const int* __restrict__ mask,
    float* __restrict__ joined) {
  const int l0 = blockIdx.x * TL;
  const int h = blockIdx.y;
  const int tid = threadIdx.x;
  const float scale = 0.036084391824351615f;  // 1/sqrt(768)

  __shared__ float kvS[NSLOT * HD];
  __shared__ float sS[TL * (WIN + 4)];
  __shared__ float vbias[NSLOT];

  const float* kh = k + (size_t)h * L_SEQ * HD;
  const float* vh = v + (size_t)h * L_SEQ * HD;
  const float* qh = q + (size_t)h * L_SEQ * HD;

  for (int c = tid; c < NSLOT * 16; c += 256) {
    const int slot = c >> 4;
    const int d4 = c & 15;
    const int raw = l0 + slot - WIN / 2;
    const int idx = min(max(raw, 0), L_SEQ - 1);
    const float4 k4 = *reinterpret_cast<const float4*>(&kh[(size_t)idx * HD + d4 * 4]);
    *reinterpret_cast<float4*>(&kvS[slot * HD + ((d4 ^ (slot & 7)) << 2)]) = k4;
  }
  if (tid < NSLOT) {
    const int raw = l0 + tid - WIN / 2;
    const int idx = min(max(raw, 0), L_SEQ - 1);
    const bool valid = (raw >= 0) && (raw < L_SEQ) && (mask[idx] != 0);
    vbias[tid] = valid ? 0.f : -INFINITY;
  }
  __syncthreads();

  const int r = tid >> 3;
  const int wg = tid & 7;
  int koff[16], kx4[16];
#pragma unroll
  for (int wi = 0; wi < 16; ++wi) {
    const int slot = r + wg * 16 + wi;
    koff[wi] = slot * HD;
    kx4[wi] = (slot & 7) << 2;
  }
  float acc[16] = {};
#pragma unroll
  for (int d4 = 0; d4 < 16; ++d4) {
    const float4 q4 = *reinterpret_cast<const float4*>(
        &qh[(size_t)(l0 + r) * HD + d4 * 4]);
    const int d44 = d4 << 2;
#pragma unroll
    for (int wi = 0; wi < 16; ++wi) {
      const float4 k4 =
          *reinterpret_cast<const float4*>(&kvS[koff[wi] + (d44 ^ kx4[wi])]);
      acc[wi] += q4.x * k4.x + q4.y * k4.y + q4.z * k4.z + q4.w * k4.w;
    }
  }
  float pv[16];
  float mloc = -INFINITY;
#pragma unroll
  for (int wi = 0; wi < 16; ++wi) {
    pv[wi] = acc[wi] * scale + vbias[r + wg * 16 + wi];
    mloc = fmaxf(mloc, pv[wi]);
  }
#pragma unroll
  for (int m = 1; m < 8; m <<= 1) mloc = fmaxf(mloc, __shfl_xor(mloc, m));
  float ssum = 0.f;
#pragma unroll
  for (int wi = 0; wi < 16; ++wi) {
    pv[wi] = __expf(pv[wi] - mloc);
    ssum += pv[wi];
  }
#pragma unroll
  for (int m = 1; m < 8; m <<= 1) ssum += __shfl_xor(ssum, m);
  const float rcp = 1.0f / ssum;
#pragma unroll
  for (int wi = 0; wi < 16; ++wi)
    sS[r * (WIN + 4) + wg * 16 + wi] = pv[wi] * rcp;
  __syncthreads();

  for (int c = tid; c < NSLOT * 16; c += 256) {
    const int slot = c >> 4;
    const int d4 = c & 15;
    const int raw = l0 + slot - WIN / 2;
    const int idx = min(max(raw, 0), L_SEQ - 1);
    const float4 v4 = *reinterpret_cast<const float4*>(&vh[(size_t)idx * HD + d4 * 4]);
    *reinterpret_cast<float4*>(&kvS[slot * HD + ((d4 ^ (slot & 7)) << 2)]) = v4;
  }
  __syncthreads();

  const int dg = tid & 7;
  float o[8] = {};
#pragma unroll 4
  for (int w = 0; w < WIN; ++w) {
    const float p = sS[r * (WIN + 4) + w];
    const int slot = r + w;
    const int base = slot * HD;
    const int x4 = (slot & 7) << 2;
    const float4 vA =
        *reinterpret_cast<const float4*>(&kvS[base + ((dg << 3) ^ x4)]);
    const float4 vB =
        *reinterpret_cast<const float4*>(&kvS[base + (((dg << 3) + 4) ^ x4)]);
    o[0] += p * vA.x; o[1] += p * vA.y; o[2] += p * vA.z; o[3] += p * vA.w;
    o[4] += p * vB.x; o[5] += p * vB.y; o[6] += p * vB.z; o[7] += p * vB.w;
  }
  float4 o0 = {o[0], o[1], o[2], o[3]};
  float4 o1 = {o[4], o[5], o[6], o[7]};
  float* dst = &joined[(size_t)(l0 + r) * D_MODEL + h * HD + dg * 8];
  *reinterpret_cast<float4*>(dst) = o0;
  *reinterpret_cast<float4*>(dst + 4) = o1;
}

// ---------------------------------------------------------------------------
// CLS attention v3: split-L flash-style decomposition.
// cls_partial: grid (NHEAD, CSPLIT), 256 threads; each block covers 128 rows.
//   Writes per-(h,split) record: {local_max, local_sum, pv[64]} (unnormalized,
//   scaled by exp(s - local_max)).
// cls_combine: grid NHEAD, 64 threads; global-max rescale + merge.
// ---------------------------------------------------------------------------
#define CSPLIT 16
#define CROWS (L_SEQ / CSPLIT)  // 128
#define CREC 66                 // floats per record

__global__ __launch_bounds__(256) void cls_partial_kernel(
    const float* __restrict__ q, const float* __restrict__ k,
    const float* __restrict__ v, const int* __restrict__ mask,
    float* __restrict__ part) {
  const int h = blockIdx.x;
  const int sp = blockIdx.y;
  const int tid = threadIdx.x;
  const int l0 = sp * CROWS;
  const float scale = 0.036084391824351615f;

  __shared__ float scS[CROWS];
  __shared__ float red[256];
  __shared__ float pvS[4][HD];

  const float* kh = k + (size_t)h * L_SEQ * HD;
  const float* vh = v + (size_t)h * L_SEQ * HD;

  // scores: 16 threads per row, 16 rows in flight, 8 iterations
  const int lq = tid >> 4;
  const int dq = tid & 15;
  const float4 q4 = *reinterpret_cast<const float4*>(
      &q[(size_t)h * L_SEQ * HD + dq * 4]);
#pragma unroll
  for (int it = 0; it < CROWS / 16; ++it) {
    const int l = l0 + it * 16 + lq;
    const float4 k4 = *reinterpret_cast<const float4*>(&kh[(size_t)l * HD + dq * 4]);
    float p = q4.x * k4.x + q4.y * k4.y + q4.z * k4.z + q4.w * k4.w;
#pragma unroll
    for (int m = 1; m < 16; m <<= 1) p += __shfl_xor(p, m);
    if (dq == 0) scS[it * 16 + lq] = (mask[l] != 0) ? p * scale : -INFINITY;
  }
  __syncthreads();

  // local max over 128 rows
  red[tid] = (tid < CROWS) ? scS[tid] : -INFINITY;
  __syncthreads();
  for (int off = 128; off > 0; off >>= 1) {
    if (tid < off) red[tid] = fmaxf(red[tid], red[tid + off]);
    __syncthreads();
  }
  const float mx = red[0];
  __syncthreads();

  // exp + local sum (guard fully-masked split: mx == -inf)
  float e = 0.f;
  if (tid < CROWS) {
    e = (mx == -INFINITY) ? 0.f : __expf(scS[tid] - mx);
    scS[tid] = e;
  }
  red[tid] = e;
  __syncthreads();
  for (int off = 128; off > 0; off >>= 1) {
    if (tid < off) red[tid] += red[tid + off];
    __syncthreads();
  }
  const float lsum = red[0];
  __syncthreads();

  // partial PV: 4-way l-split, 64 d-lanes; 32 unrolled iterations
  const int lg = tid >> 6;
  const int d = tid & 63;
  float acc = 0.f;
#pragma unroll 8
  for (int it = 0; it < CROWS / 4; ++it) {
    const int ll = lg + it * 4;
    acc += scS[ll] * vh[(size_t)(l0 + ll) * HD + d];
  }
  pvS[lg][d] = acc;
  __syncthreads();

  float* rec = &part[(size_t)(h * CSPLIT + sp) * CREC];
  if (tid == 0) {
    rec[0] = mx;
    rec[1] = lsum;
  }
  if (tid < HD)
    rec[2 + tid] = pvS[0][tid] + pvS[1][tid] + pvS[2][tid] + pvS[3][tid];
}

__global__ __launch_bounds__(64) void cls_combine_kernel(
    const float* __restrict__ part, float* __restrict__ joined) {
  const int h = blockIdx.x;
  const int d = threadIdx.x;

  float gmax = -INFINITY;
#pragma unroll
  for (int sp = 0; sp < CSPLIT; ++sp)
    gmax = fmaxf(gmax, part[(size_t)(h * CSPLIT + sp) * CREC]);

  float total = 0.f, acc = 0.f;
#pragma unroll
  for (int sp = 0; sp < CSPLIT; ++sp) {
    const float* rec = &part[(size_t)(h * CSPLIT + sp) * CREC];
    const float mxi = rec[0];
    const float w = (mxi == -INFINITY) ? 0.f : __expf(mxi - gmax);
    total += w * rec[1];
    acc += w * rec[2 + d];
  }
  joined[(size_t)h * HD + d] = acc / total;  // row 0, col h*64+d
}

// ---------------------------------------------------------------------------
extern "C" void kernel_launch(void* const* d_in, const int* in_sizes, int n_in,
                              void* d_out, int out_size, void* d_ws,
                              size_t ws_size, hipStream_t stream) {
  const float* emb   = (const float*)d_in[0];
  const int*   mask  = (const int*)d_in[1];
  const float* W_qkv = (const float*)d_in[2];
  const float* b_qkv = (const float*)d_in[3];
  const float* W_o   = (const float*)d_in[4];
  const float* b_o   = (const float*)d_in[5];
  float* out = (float*)d_out;

  float* ws = (float*)d_ws;
  float* qkv = ws;                                   // 2048*2304
  float* qbuf = qkv + (size_t)L_SEQ * QKV_N;
  float* kbuf = qbuf + (size_t)NHEAD * L_SEQ * HD;
  float* vbuf = kbuf + (size_t)NHEAD * L_SEQ * HD;
  float* part = vbuf + (size_t)NHEAD * L_SEQ * HD;   // 12*16*66 floats
  float* joined = qkv;  // qkv dead after rope_split

  gemm_bias_kernel<2, 2><<<dim3(QKV_N / 128, L_SEQ / 128), 256, 0, stream>>>(
      emb, W_qkv, b_qkv, qkv, L_SEQ, QKV_N, D_MODEL);

  rope_split_kernel<<<dim3(L_SEQ, NHEAD), 64, 0, stream>>>(qkv, qbuf, kbuf, vbuf);

  cls_partial_kernel<<<dim3(NHEAD, CSPLIT), 256, 0, stream>>>(qbuf, kbuf, vbuf,
                                                              mask, part);

  win_attn_kernel<<<dim3(L_SEQ / TL, NHEAD), 256, 0, stream>>>(qbuf, kbuf, vbuf,
                                                               mask, joined);

  cls_combine_kernel<<<NHEAD, 64, 0, stream>>>(part, joined);

  gemm_bias_kernel<2, 1><<<dim3(D_MODEL / 64, L_SEQ / 128), 256, 0, stream>>>(
      joined, W_o, b_o, out, L_SEQ, D_MODEL, D_MODEL);
}

// Round 5
// 207.974 us; speedup vs baseline: 2.6860x; 1.7328x over previous
//
#include <hip/hip_runtime.h>
#include <hip/hip_bf16.h>
#include <cmath>

#define D_MODEL 768
#define NHEAD 12
#define HD 64
#define L_SEQ 2048
#define WIN 128
#define QKV_N (3 * D_MODEL)

typedef _Float16 half8 __attribute__((ext_vector_type(8)));
typedef _Float16 half4v __attribute__((ext_vector_type(4)));
typedef float floatx4 __attribute__((ext_vector_type(4)));

// ---------------------------------------------------------------------------
// fp32 -> fp16 elementwise (n divisible by 1024)
// ---------------------------------------------------------------------------
__global__ __launch_bounds__(256) void cvt16_kernel(const float* __restrict__ In,
                                                    _Float16* __restrict__ Out,
                                                    int n) {
  const int i = (blockIdx.x * 256 + threadIdx.x) * 4;
  if (i < n) {
    const float4 v = *reinterpret_cast<const float4*>(&In[i]);
    half4v h = {(_Float16)v.x, (_Float16)v.y, (_Float16)v.z, (_Float16)v.w};
    *reinterpret_cast<half4v*>(&Out[i]) = h;
  }
}

// ---------------------------------------------------------------------------
// fp32 [R][Cn] -> fp16 transposed [Cn][R]. 64x64 LDS tile. R,Cn divisible by 64.
// ---------------------------------------------------------------------------
__global__ __launch_bounds__(256) void cvt_transpose16_kernel(
    const float* __restrict__ In, _Float16* __restrict__ Out, int R, int Cn) {
  __shared__ float tile[64][68];
  const int tid = threadIdx.x;
  const int r0 = blockIdx.y * 64;
  const int c0 = blockIdx.x * 64;
  const int tr = tid >> 4;         // 0..15
  const int tc4 = (tid & 15) * 4;  // 0..60
#pragma unroll
  for (int rr = 0; rr < 4; ++rr) {
    const int r = rr * 16 + tr;
    const float4 v =
        *reinterpret_cast<const float4*>(&In[(size_t)(r0 + r) * Cn + c0 + tc4]);
    tile[r][tc4 + 0] = v.x;
    tile[r][tc4 + 1] = v.y;
    tile[r][tc4 + 2] = v.z;
    tile[r][tc4 + 3] = v.w;
  }
  __syncthreads();
#pragma unroll
  for (int cc = 0; cc < 4; ++cc) {
    const int c = cc * 16 + tr;  // local col -> Out row (c0+c)
    half4v h = {(_Float16)tile[tc4 + 0][c], (_Float16)tile[tc4 + 1][c],
                (_Float16)tile[tc4 + 2][c], (_Float16)tile[tc4 + 3][c]};
    *reinterpret_cast<half4v*>(&Out[(size_t)(c0 + c) * R + r0 + tc4]) = h;
  }
}

// ---------------------------------------------------------------------------
// fp16 MFMA GEMM: C[M][N] = A[M][K] @ BT[N][K]^T + bias, fp32 out.
// Tile BM x 128, BK=32, 256 threads = 4 waves (2x2), 16x16x32 MFMA.
// A,BT row-major along K -> identical staging. LDS rows padded to 40 halfs.
// C/D layout (m89-verified): col = lane&15, row = (lane>>4)*4 + j.
// ---------------------------------------------------------------------------
template <int BM>
__global__ __launch_bounds__(256) void gemm16_kernel(
    const _Float16* __restrict__ A, const _Float16* __restrict__ BT,
    const float* __restrict__ bias, float* __restrict__ C, int M, int N,
    int K) {
  constexpr int BN = 128;
  constexpr int LDK = 40;      // padded row (80 B)
  constexpr int MF = BM / 32;  // m-fragments per wave

  __shared__ __align__(16) _Float16 At[BM * LDK];
  __shared__ __align__(16) _Float16 Bt[BN * LDK];

  const int tid = threadIdx.x;
  const int row0 = blockIdx.y * BM;
  const int col0 = blockIdx.x * BN;
  const int wv = tid >> 6;
  const int lane = tid & 63;
  const int wr = wv >> 1;
  const int wc = wv & 1;
  const int lrow = lane & 15;
  const int lk = lane >> 4;  // 0..3

  floatx4 acc[MF][4];
#pragma unroll
  for (int m = 0; m < MF; ++m)
#pragma unroll
    for (int n = 0; n < 4; ++n) acc[m][n] = (floatx4){0.f, 0.f, 0.f, 0.f};

  for (int k0 = 0; k0 < K; k0 += 32) {
#pragma unroll
    for (int c = tid; c < BM * 4; c += 256) {
      const int r = c >> 2, seg = c & 3;
      *reinterpret_cast<half8*>(&At[r * LDK + seg * 8]) =
          *reinterpret_cast<const half8*>(
              &A[(size_t)(row0 + r) * K + k0 + seg * 8]);
    }
#pragma unroll
    for (int c = tid; c < BN * 4; c += 256) {
      const int r = c >> 2, seg = c & 3;
      *reinterpret_cast<half8*>(&Bt[r * LDK + seg * 8]) =
          *reinterpret_cast<const half8*>(
              &BT[(size_t)(col0 + r) * K + k0 + seg * 8]);
    }
    __syncthreads();

    half8 af[MF], bf[4];
#pragma unroll
    for (int m = 0; m < MF; ++m)
      af[m] = *reinterpret_cast<const half8*>(
          &At[(wr * (BM / 2) + m * 16 + lrow) * LDK + lk * 8]);
#pragma unroll
    for (int n = 0; n < 4; ++n)
      bf[n] = *reinterpret_cast<const half8*>(
          &Bt[(wc * 64 + n * 16 + lrow) * LDK + lk * 8]);
#pragma unroll
    for (int m = 0; m < MF; ++m)
#pragma unroll
      for (int n = 0; n < 4; ++n)
        acc[m][n] = __builtin_amdgcn_mfma_f32_16x16x32_f16(af[m], bf[n],
                                                           acc[m][n], 0, 0, 0);
    __syncthreads();
  }

#pragma unroll
  for (int m = 0; m < MF; ++m)
#pragma unroll
    for (int n = 0; n < 4; ++n) {
      const int col = col0 + wc * 64 + n * 16 + lrow;
      const float bb = bias[col];
#pragma unroll
      for (int j = 0; j < 4; ++j) {
        const int row = row0 + wr * (BM / 2) + m * 16 + lk * 4 + j;
        C[(size_t)row * N + col] = acc[m][n][j] + bb;
      }
    }
}

// ---------------------------------------------------------------------------
// RoPE + split (unchanged).
// ---------------------------------------------------------------------------
__global__ __launch_bounds__(64) void rope_split_kernel(
    const float* __restrict__ qkv, float* __restrict__ q,
    float* __restrict__ k, float* __restrict__ v) {
  const int l = blockIdx.x;
  const int h = blockIdx.y;
  const int d = threadIdx.x;
  const int i = d & 31;

  const float inv = (float)(1.0 / pow(10000.0, (double)(2 * i) / 64.0));
  const float ang = (float)l * inv;
  const float c = cosf(ang);
  const float s = sinf(ang);

  const size_t base = (size_t)l * QKV_N + h * HD;
  const size_t obase = ((size_t)h * L_SEQ + l) * HD + d;

  {
    const float x = qkv[base + d];
    const float xp = qkv[base + (d ^ 32)];
    q[obase] = (d < 32) ? (x * c - xp * s) : (xp * s + x * c);
  }
  {
    const float x = qkv[base + D_MODEL + d];
    const float xp = qkv[base + D_MODEL + (d ^ 32)];
    k[obase] = (d < 32) ? (x * c - xp * s) : (xp * s + x * c);
  }
  v[obase] = qkv[base + 2 * D_MODEL + d];
}

// ---------------------------------------------------------------------------
// Window attention (as R4, but writes fp16 joined).
// ---------------------------------------------------------------------------
#define TL 32
#define NSLOT (TL + WIN)  // 160

__global__ __launch_bounds__(256) void win_attn_kernel(
    const float* __restrict__ q, const float* __restrict__ k,
    const float* __restrict__ v, const int* __restrict__ mask,
    _Float16* __restrict__ joined) {
  const int l0 = blockIdx.x * TL;
  const int h = blockIdx.y;
  const int tid = threadIdx.x;
  const float scale = 0.036084391824351615f;  // 1/sqrt(768)

  __shared__ float kvS[NSLOT * HD];
  __shared__ float sS[TL * (WIN + 4)];
  __shared__ float vbias[NSLOT];

  const float* kh = k + (size_t)h * L_SEQ * HD;
  const float* vh = v + (size_t)h * L_SEQ * HD;
  const float* qh = q + (size_t)h * L_SEQ * HD;

  for (int c = tid; c < NSLOT * 16; c += 256) {
    const int slot = c >> 4;
    const int d4 = c & 15;
    const int raw = l0 + slot - WIN / 2;
    const int idx = min(max(raw, 0), L_SEQ - 1);
    const float4 k4 =
        *reinterpret_cast<const float4*>(&kh[(size_t)idx * HD + d4 * 4]);
    *reinterpret_cast<float4*>(&kvS[slot * HD + ((d4 ^ (slot & 7)) << 2)]) = k4;
  }
  if (tid < NSLOT) {
    const int raw = l0 + tid - WIN / 2;
    const int idx = min(max(raw, 0), L_SEQ - 1);
    const bool valid = (raw >= 0) && (raw < L_SEQ) && (mask[idx] != 0);
    vbias[tid] = valid ? 0.f : -INFINITY;
  }
  __syncthreads();

  const int r = tid >> 3;
  const int wg = tid & 7;
  int koff[16], kx4[16];
#pragma unroll
  for (int wi = 0; wi < 16; ++wi) {
    const int slot = r + wg * 16 + wi;
    koff[wi] = slot * HD;
    kx4[wi] = (slot & 7) << 2;
  }
  float acc[16] = {};
#pragma unroll
  for (int d4 = 0; d4 < 16; ++d4) {
    const float4 q4 = *reinterpret_cast<const float4*>(
        &qh[(size_t)(l0 + r) * HD + d4 * 4]);
    const int d44 = d4 << 2;
#pragma unroll
    for (int wi = 0; wi < 16; ++wi) {
      const float4 k4 =
          *reinterpret_cast<const float4*>(&kvS[koff[wi] + (d44 ^ kx4[wi])]);
      acc[wi] += q4.x * k4.x + q4.y * k4.y + q4.z * k4.z + q4.w * k4.w;
    }
  }
  float pv[16];
  float mloc = -INFINITY;
#pragma unroll
  for (int wi = 0; wi < 16; ++wi) {
    pv[wi] = acc[wi] * scale + vbias[r + wg * 16 + wi];
    mloc = fmaxf(mloc, pv[wi]);
  }
#pragma unroll
  for (int m = 1; m < 8; m <<= 1) mloc = fmaxf(mloc, __shfl_xor(mloc, m));
  float ssum = 0.f;
#pragma unroll
  for (int wi = 0; wi < 16; ++wi) {
    pv[wi] = __expf(pv[wi] - mloc);
    ssum += pv[wi];
  }
#pragma unroll
  for (int m = 1; m < 8; m <<= 1) ssum += __shfl_xor(ssum, m);
  const float rcp = 1.0f / ssum;
#pragma unroll
  for (int wi = 0; wi < 16; ++wi)
    sS[r * (WIN + 4) + wg * 16 + wi] = pv[wi] * rcp;
  __syncthreads();

  for (int c = tid; c < NSLOT * 16; c += 256) {
    const int slot = c >> 4;
    const int d4 = c & 15;
    const int raw = l0 + slot - WIN / 2;
    const int idx = min(max(raw, 0), L_SEQ - 1);
    const float4 v4 =
        *reinterpret_cast<const float4*>(&vh[(size_t)idx * HD + d4 * 4]);
    *reinterpret_cast<float4*>(&kvS[slot * HD + ((d4 ^ (slot & 7)) << 2)]) = v4;
  }
  __syncthreads();

  const int dg = tid & 7;
  float o[8] = {};
#pragma unroll 4
  for (int w = 0; w < WIN; ++w) {
    const float p = sS[r * (WIN + 4) + w];
    const int slot = r + w;
    const int base = slot * HD;
    const int x4 = (slot & 7) << 2;
    const float4 vA =
        *reinterpret_cast<const float4*>(&kvS[base + ((dg << 3) ^ x4)]);
    const float4 vB =
        *reinterpret_cast<const float4*>(&kvS[base + (((dg << 3) + 4) ^ x4)]);
    o[0] += p * vA.x; o[1] += p * vA.y; o[2] += p * vA.z; o[3] += p * vA.w;
    o[4] += p * vB.x; o[5] += p * vB.y; o[6] += p * vB.z; o[7] += p * vB.w;
  }
  half8 hv = {(_Float16)o[0], (_Float16)o[1], (_Float16)o[2], (_Float16)o[3],
              (_Float16)o[4], (_Float16)o[5], (_Float16)o[6], (_Float16)o[7]};
  *reinterpret_cast<half8*>(
      &joined[(size_t)(l0 + r) * D_MODEL + h * HD + dg * 8]) = hv;
}

// ---------------------------------------------------------------------------
// CLS attention split-L (as R4); combine writes fp16 joined row 0.
// ---------------------------------------------------------------------------
#define CSPLIT 16
#define CROWS (L_SEQ / CSPLIT)  // 128
#define CREC 66

__global__ __launch_bounds__(256) void cls_partial_kernel(
    const float* __restrict__ q, const float* __restrict__ k,
    const float* __restrict__ v, const int* __restrict__ mask,
    float* __restrict__ part) {
  const int h = blockIdx.x;
  const int sp = blockIdx.y;
  const int tid = threadIdx.x;
  const int l0 = sp * CROWS;
  const float scale = 0.036084391824351615f;

  __shared__ float scS[CROWS];
  __shared__ float red[256];
  __shared__ float pvS[4][HD];

  const float* kh = k + (size_t)h * L_SEQ * HD;
  const float* vh = v + (size_t)h * L_SEQ * HD;

  const int lq = tid >> 4;
  const int dq = tid & 15;
  const float4 q4 =
      *reinterpret_cast<const float4*>(&q[(size_t)h * L_SEQ * HD + dq * 4]);
#pragma unroll
  for (int it = 0; it < CROWS / 16; ++it) {
    const int l = l0 + it * 16 + lq;
    const float4 k4 =
        *reinterpret_cast<const float4*>(&kh[(size_t)l * HD + dq * 4]);
    float p = q4.x * k4.x + q4.y * k4.y + q4.z * k4.z + q4.w * k4.w;
#pragma unroll
    for (int m = 1; m < 16; m <<= 1) p += __shfl_xor(p, m);
    if (dq == 0) scS[it * 16 + lq] = (mask[l] != 0) ? p * scale : -INFINITY;
  }
  __syncthreads();

  red[tid] = (tid < CROWS) ? scS[tid] : -INFINITY;
  __syncthreads();
  for (int off = 128; off > 0; off >>= 1) {
    if (tid < off) red[tid] = fmaxf(red[tid], red[tid + off]);
    __syncthreads();
  }
  const float mx = red[0];
  __syncthreads();

  float e = 0.f;
  if (tid < CROWS) {
    e = (mx == -INFINITY) ? 0.f : __expf(scS[tid] - mx);
    scS[tid] = e;
  }
  red[tid] = e;
  __syncthreads();
  for (int off = 128; off > 0; off >>= 1) {
    if (tid < off) red[tid] += red[tid + off];
    __syncthreads();
  }
  const float lsum = red[0];
  __syncthreads();

  const int lg = tid >> 6;
  const int d = tid & 63;
  float acc = 0.f;
#pragma unroll 8
  for (int it = 0; it < CROWS / 4; ++it) {
    const int ll = lg + it * 4;
    acc += scS[ll] * vh[(size_t)(l0 + ll) * HD + d];
  }
  pvS[lg][d] = acc;
  __syncthreads();

  float* rec = &part[(size_t)(h * CSPLIT + sp) * CREC];
  if (tid == 0) {
    rec[0] = mx;
    rec[1] = lsum;
  }
  if (tid < HD)
    rec[2 + tid] = pvS[0][tid] + pvS[1][tid] + pvS[2][tid] + pvS[3][tid];
}

__global__ __launch_bounds__(64) void cls_combine_kernel(
    const float* __restrict__ part, _Float16* __restrict__ joined) {
  const int h = blockIdx.x;
  const int d = threadIdx.x;

  float gmax = -INFINITY;
#pragma unroll
  for (int sp = 0; sp < CSPLIT; ++sp)
    gmax = fmaxf(gmax, part[(size_t)(h * CSPLIT + sp) * CREC]);

  float total = 0.f, acc = 0.f;
#pragma unroll
  for (int sp = 0; sp < CSPLIT; ++sp) {
    const float* rec = &part[(size_t)(h * CSPLIT + sp) * CREC];
    const float mxi = rec[0];
    const float w = (mxi == -INFINITY) ? 0.f : __expf(mxi - gmax);
    total += w * rec[1];
    acc += w * rec[2 + d];
  }
  joined[(size_t)h * HD + d] = (_Float16)(acc / total);
}

// ---------------------------------------------------------------------------
extern "C" void kernel_launch(void* const* d_in, const int* in_sizes, int n_in,
                              void* d_out, int out_size, void* d_ws,
                              size_t ws_size, hipStream_t stream) {
  const float* emb   = (const float*)d_in[0];
  const int*   mask  = (const int*)d_in[1];
  const float* W_qkv = (const float*)d_in[2];
  const float* b_qkv = (const float*)d_in[3];
  const float* W_o   = (const float*)d_in[4];
  const float* b_o   = (const float*)d_in[5];
  float* out = (float*)d_out;

  float* ws = (float*)d_ws;
  float* qkv = ws;                                    // 2048*2304 fp32
  float* qbuf = qkv + (size_t)L_SEQ * QKV_N;          // 4,718,592
  float* kbuf = qbuf + (size_t)NHEAD * L_SEQ * HD;
  float* vbuf = kbuf + (size_t)NHEAD * L_SEQ * HD;
  float* part = vbuf + (size_t)NHEAD * L_SEQ * HD;    // 12*16*66
  float* fp16pool = part + 12672;
  _Float16* A16    = (_Float16*)fp16pool;                      // 2048*768
  _Float16* Wq16T  = A16 + (size_t)L_SEQ * D_MODEL;            // 2304*768
  _Float16* Wo16T  = Wq16T + (size_t)QKV_N * D_MODEL;          // 768*768
  _Float16* J16    = (_Float16*)qkv;  // alias: qkv dead after rope_split

  // conversions
  cvt16_kernel<<<(L_SEQ * D_MODEL) / 1024, 256, 0, stream>>>(
      emb, A16, L_SEQ * D_MODEL);
  cvt_transpose16_kernel<<<dim3(QKV_N / 64, D_MODEL / 64), 256, 0, stream>>>(
      W_qkv, Wq16T, D_MODEL, QKV_N);
  cvt_transpose16_kernel<<<dim3(D_MODEL / 64, D_MODEL / 64), 256, 0, stream>>>(
      W_o, Wo16T, D_MODEL, D_MODEL);

  // QKV GEMM (fp16 MFMA)
  gemm16_kernel<128><<<dim3(QKV_N / 128, L_SEQ / 128), 256, 0, stream>>>(
      A16, Wq16T, b_qkv, qkv, L_SEQ, QKV_N, D_MODEL);

  rope_split_kernel<<<dim3(L_SEQ, NHEAD), 64, 0, stream>>>(qkv, qbuf, kbuf,
                                                           vbuf);

  cls_partial_kernel<<<dim3(NHEAD, CSPLIT), 256, 0, stream>>>(qbuf, kbuf, vbuf,
                                                              mask, part);

  win_attn_kernel<<<dim3(L_SEQ / TL, NHEAD), 256, 0, stream>>>(qbuf, kbuf, vbuf,
                                                               mask, J16);

  cls_combine_kernel<<<NHEAD, 64, 0, stream>>>(part, J16);

  // Output GEMM (fp16 MFMA)
  gemm16_kernel<64><<<dim3(D_MODEL / 128, L_SEQ / 64), 256, 0, stream>>>(
      J16, Wo16T, b_o, out, L_SEQ, D_MODEL, D_MODEL);
}

// Round 6
// 204.124 us; speedup vs baseline: 2.7366x; 1.0189x over previous
//
#include <hip/hip_runtime.h>
#include <hip/hip_bf16.h>
#include <cmath>

#define D_MODEL 768
#define NHEAD 12
#define HD 64
#define L_SEQ 2048
#define WIN 128
#define QKV_N (3 * D_MODEL)

typedef _Float16 half8 __attribute__((ext_vector_type(8)));
typedef _Float16 half4v __attribute__((ext_vector_type(4)));
typedef float floatx4 __attribute__((ext_vector_type(4)));

// ---------------------------------------------------------------------------
// fp32 -> fp16 elementwise (n divisible by 1024)
// ---------------------------------------------------------------------------
__global__ __launch_bounds__(256) void cvt16_kernel(const float* __restrict__ In,
                                                    _Float16* __restrict__ Out,
                                                    int n) {
  const int i = (blockIdx.x * 256 + threadIdx.x) * 4;
  if (i < n) {
    const float4 v = *reinterpret_cast<const float4*>(&In[i]);
    half4v h = {(_Float16)v.x, (_Float16)v.y, (_Float16)v.z, (_Float16)v.w};
    *reinterpret_cast<half4v*>(&Out[i]) = h;
  }
}

// ---------------------------------------------------------------------------
// fp32 [R][Cn] -> fp16 transposed [Cn][R]. 64x64 LDS tile.
// ---------------------------------------------------------------------------
__global__ __launch_bounds__(256) void cvt_transpose16_kernel(
    const float* __restrict__ In, _Float16* __restrict__ Out, int R, int Cn) {
  __shared__ float tile[64][68];
  const int tid = threadIdx.x;
  const int r0 = blockIdx.y * 64;
  const int c0 = blockIdx.x * 64;
  const int tr = tid >> 4;
  const int tc4 = (tid & 15) * 4;
#pragma unroll
  for (int rr = 0; rr < 4; ++rr) {
    const int r = rr * 16 + tr;
    const float4 v =
        *reinterpret_cast<const float4*>(&In[(size_t)(r0 + r) * Cn + c0 + tc4]);
    tile[r][tc4 + 0] = v.x;
    tile[r][tc4 + 1] = v.y;
    tile[r][tc4 + 2] = v.z;
    tile[r][tc4 + 3] = v.w;
  }
  __syncthreads();
#pragma unroll
  for (int cc = 0; cc < 4; ++cc) {
    const int c = cc * 16 + tr;
    half4v h = {(_Float16)tile[tc4 + 0][c], (_Float16)tile[tc4 + 1][c],
                (_Float16)tile[tc4 + 2][c], (_Float16)tile[tc4 + 3][c]};
    *reinterpret_cast<half4v*>(&Out[(size_t)(c0 + c) * R + r0 + tc4]) = h;
  }
}

// ---------------------------------------------------------------------------
// fp16 MFMA GEMM: C[M][N] = A[M][K] @ BT[N][K]^T + bias, fp32 out.
// (unchanged from R5 — validated)
// ---------------------------------------------------------------------------
template <int BM>
__global__ __launch_bounds__(256) void gemm16_kernel(
    const _Float16* __restrict__ A, const _Float16* __restrict__ BT,
    const float* __restrict__ bias, float* __restrict__ C, int M, int N,
    int K) {
  constexpr int BN = 128;
  constexpr int LDK = 40;
  constexpr int MF = BM / 32;

  __shared__ __align__(16) _Float16 At[BM * LDK];
  __shared__ __align__(16) _Float16 Bt[BN * LDK];

  const int tid = threadIdx.x;
  const int row0 = blockIdx.y * BM;
  const int col0 = blockIdx.x * BN;
  const int wv = tid >> 6;
  const int lane = tid & 63;
  const int wr = wv >> 1;
  const int wc = wv & 1;
  const int lrow = lane & 15;
  const int lk = lane >> 4;

  floatx4 acc[MF][4];
#pragma unroll
  for (int m = 0; m < MF; ++m)
#pragma unroll
    for (int n = 0; n < 4; ++n) acc[m][n] = (floatx4){0.f, 0.f, 0.f, 0.f};

  for (int k0 = 0; k0 < K; k0 += 32) {
#pragma unroll
    for (int c = tid; c < BM * 4; c += 256) {
      const int r = c >> 2, seg = c & 3;
      *reinterpret_cast<half8*>(&At[r * LDK + seg * 8]) =
          *reinterpret_cast<const half8*>(
              &A[(size_t)(row0 + r) * K + k0 + seg * 8]);
    }
#pragma unroll
    for (int c = tid; c < BN * 4; c += 256) {
      const int r = c >> 2, seg = c & 3;
      *reinterpret_cast<half8*>(&Bt[r * LDK + seg * 8]) =
          *reinterpret_cast<const half8*>(
              &BT[(size_t)(col0 + r) * K + k0 + seg * 8]);
    }
    __syncthreads();

    half8 af[MF], bf[4];
#pragma unroll
    for (int m = 0; m < MF; ++m)
      af[m] = *reinterpret_cast<const half8*>(
          &At[(wr * (BM / 2) + m * 16 + lrow) * LDK + lk * 8]);
#pragma unroll
    for (int n = 0; n < 4; ++n)
      bf[n] = *reinterpret_cast<const half8*>(
          &Bt[(wc * 64 + n * 16 + lrow) * LDK + lk * 8]);
#pragma unroll
    for (int m = 0; m < MF; ++m)
#pragma unroll
      for (int n = 0; n < 4; ++n)
        acc[m][n] = __builtin_amdgcn_mfma_f32_16x16x32_f16(af[m], bf[n],
                                                           acc[m][n], 0, 0, 0);
    __syncthreads();
  }

#pragma unroll
  for (int m = 0; m < MF; ++m)
#pragma unroll
    for (int n = 0; n < 4; ++n) {
      const int col = col0 + wc * 64 + n * 16 + lrow;
      const float bb = bias[col];
#pragma unroll
      for (int j = 0; j < 4; ++j) {
        const int row = row0 + wr * (BM / 2) + m * 16 + lk * 4 + j;
        C[(size_t)row * N + col] = acc[m][n][j] + bb;
      }
    }
}

// ---------------------------------------------------------------------------
// RoPE + split (unchanged).
// ---------------------------------------------------------------------------
__global__ __launch_bounds__(64) void rope_split_kernel(
    const float* __restrict__ qkv, float* __restrict__ q,
    float* __restrict__ k, float* __restrict__ v) {
  const int l = blockIdx.x;
  const int h = blockIdx.y;
  const int d = threadIdx.x;
  const int i = d & 31;

  const float inv = (float)(1.0 / pow(10000.0, (double)(2 * i) / 64.0));
  const float ang = (float)l * inv;
  const float c = cosf(ang);
  const float s = sinf(ang);

  const size_t base = (size_t)l * QKV_N + h * HD;
  const size_t obase = ((size_t)h * L_SEQ + l) * HD + d;

  {
    const float x = qkv[base + d];
    const float xp = qkv[base + (d ^ 32)];
    q[obase] = (d < 32) ? (x * c - xp * s) : (xp * s + x * c);
  }
  {
    const float x = qkv[base + D_MODEL + d];
    const float xp = qkv[base + D_MODEL + (d ^ 32)];
    k[obase] = (d < 32) ? (x * c - xp * s) : (xp * s + x * c);
  }
  v[obase] = qkv[base + 2 * D_MODEL + d];
}

// ---------------------------------------------------------------------------
// Window attention v3: swizzle fixed to include slot bit-4 (wg bits), so the
// score-phase ds_read_b128 is 2-way (free) instead of 8-way. sS -> fp16
// (LDS 58.9 -> 50.0 KB => 3 blocks/CU).
// ---------------------------------------------------------------------------
#define TL 32
#define NSLOT (TL + WIN)  // 160
#define SWZ(s) (((s) ^ ((s) >> 4)) & 7)

__global__ __launch_bounds__(256) void win_attn_kernel(
    const float* __restrict__ q, const float* __restrict__ k,
    const float* __restrict__ v, const int* __restrict__ mask,
    _Float16* __restrict__ joined) {
  const int l0 = blockIdx.x * TL;
  const int h = blockIdx.y;
  const int tid = threadIdx.x;
  const float scale = 0.036084391824351615f;  // 1/sqrt(768)

  __shared__ float kvS[NSLOT * HD];
  __shared__ _Float16 sS16[TL * (WIN + 4)];
  __shared__ float vbias[NSLOT];

  const float* kh = k + (size_t)h * L_SEQ * HD;
  const float* vh = v + (size_t)h * L_SEQ * HD;
  const float* qh = q + (size_t)h * L_SEQ * HD;

  // ---- stage K (swizzled) ----
  for (int c = tid; c < NSLOT * 16; c += 256) {
    const int slot = c >> 4;
    const int d4 = c & 15;
    const int raw = l0 + slot - WIN / 2;
    const int idx = min(max(raw, 0), L_SEQ - 1);
    const float4 k4 =
        *reinterpret_cast<const float4*>(&kh[(size_t)idx * HD + d4 * 4]);
    *reinterpret_cast<float4*>(&kvS[slot * HD + ((d4 ^ SWZ(slot)) << 2)]) = k4;
  }
  if (tid < NSLOT) {
    const int raw = l0 + tid - WIN / 2;
    const int idx = min(max(raw, 0), L_SEQ - 1);
    const bool valid = (raw >= 0) && (raw < L_SEQ) && (mask[idx] != 0);
    vbias[tid] = valid ? 0.f : -INFINITY;
  }
  __syncthreads();

  // ---- scores: thread (r = tid>>3, wg = tid&7) owns 16 w values ----
  const int r = tid >> 3;
  const int wg = tid & 7;
  int koff[16], kx4[16];
#pragma unroll
  for (int wi = 0; wi < 16; ++wi) {
    const int slot = r + wg * 16 + wi;
    koff[wi] = slot * HD;
    kx4[wi] = SWZ(slot) << 2;
  }
  float acc[16] = {};
#pragma unroll
  for (int d4 = 0; d4 < 16; ++d4) {
    const float4 q4 = *reinterpret_cast<const float4*>(
        &qh[(size_t)(l0 + r) * HD + d4 * 4]);
    const int d44 = d4 << 2;
#pragma unroll
    for (int wi = 0; wi < 16; ++wi) {
      const float4 k4 =
          *reinterpret_cast<const float4*>(&kvS[koff[wi] + (d44 ^ kx4[wi])]);
      acc[wi] += q4.x * k4.x + q4.y * k4.y + q4.z * k4.z + q4.w * k4.w;
    }
  }
  float pv[16];
  float mloc = -INFINITY;
#pragma unroll
  for (int wi = 0; wi < 16; ++wi) {
    pv[wi] = acc[wi] * scale + vbias[r + wg * 16 + wi];
    mloc = fmaxf(mloc, pv[wi]);
  }
#pragma unroll
  for (int m = 1; m < 8; m <<= 1) mloc = fmaxf(mloc, __shfl_xor(mloc, m));
  float ssum = 0.f;
#pragma unroll
  for (int wi = 0; wi < 16; ++wi) {
    pv[wi] = __expf(pv[wi] - mloc);
    ssum += pv[wi];
  }
#pragma unroll
  for (int m = 1; m < 8; m <<= 1) ssum += __shfl_xor(ssum, m);
  const float rcp = 1.0f / ssum;
#pragma unroll
  for (int wi = 0; wi < 16; ++wi)
    sS16[r * (WIN + 4) + wg * 16 + wi] = (_Float16)(pv[wi] * rcp);
  __syncthreads();

  // ---- re-stage with V (same swizzle) ----
  for (int c = tid; c < NSLOT * 16; c += 256) {
    const int slot = c >> 4;
    const int d4 = c & 15;
    const int raw = l0 + slot - WIN / 2;
    const int idx = min(max(raw, 0), L_SEQ - 1);
    const float4 v4 =
        *reinterpret_cast<const float4*>(&vh[(size_t)idx * HD + d4 * 4]);
    *reinterpret_cast<float4*>(&kvS[slot * HD + ((d4 ^ SWZ(slot)) << 2)]) = v4;
  }
  __syncthreads();

  // ---- PV: thread (r = tid>>3, dg = tid&7) owns 8 d values ----
  const int dg = tid & 7;
  float o[8] = {};
#pragma unroll 4
  for (int w = 0; w < WIN; ++w) {
    const float p = (float)sS16[r * (WIN + 4) + w];
    const int slot = r + w;
    const int base = slot * HD;
    const int x4 = SWZ(slot) << 2;
    const float4 vA =
        *reinterpret_cast<const float4*>(&kvS[base + ((dg << 3) ^ x4)]);
    const float4 vB =
        *reinterpret_cast<const float4*>(&kvS[base + (((dg << 3) + 4) ^ x4)]);
    o[0] += p * vA.x; o[1] += p * vA.y; o[2] += p * vA.z; o[3] += p * vA.w;
    o[4] += p * vB.x; o[5] += p * vB.y; o[6] += p * vB.z; o[7] += p * vB.w;
  }
  half8 hv = {(_Float16)o[0], (_Float16)o[1], (_Float16)o[2], (_Float16)o[3],
              (_Float16)o[4], (_Float16)o[5], (_Float16)o[6], (_Float16)o[7]};
  *reinterpret_cast<half8*>(
      &joined[(size_t)(l0 + r) * D_MODEL + h * HD + dg * 8]) = hv;
}

// ---------------------------------------------------------------------------
// CLS attention split-L (unchanged from R5).
// ---------------------------------------------------------------------------
#define CSPLIT 16
#define CROWS (L_SEQ / CSPLIT)  // 128
#define CREC 66

__global__ __launch_bounds__(256) void cls_partial_kernel(
    const float* __restrict__ q, const float* __restrict__ k,
    const float* __restrict__ v, const int* __restrict__ mask,
    float* __restrict__ part) {
  const int h = blockIdx.x;
  const int sp = blockIdx.y;
  const int tid = threadIdx.x;
  const int l0 = sp * CROWS;
  const float scale = 0.036084391824351615f;

  __shared__ float scS[CROWS];
  __shared__ float red[256];
  __shared__ float pvS[4][HD];

  const float* kh = k + (size_t)h * L_SEQ * HD;
  const float* vh = v + (size_t)h * L_SEQ * HD;

  const int lq = tid >> 4;
  const int dq = tid & 15;
  const float4 q4 =
      *reinterpret_cast<const float4*>(&q[(size_t)h * L_SEQ * HD + dq * 4]);
#pragma unroll
  for (int it = 0; it < CROWS / 16; ++it) {
    const int l = l0 + it * 16 + lq;
    const float4 k4 =
        *reinterpret_cast<const float4*>(&kh[(size_t)l * HD + dq * 4]);
    float p = q4.x * k4.x + q4.y * k4.y + q4.z * k4.z + q4.w * k4.w;
#pragma unroll
    for (int m = 1; m < 16; m <<= 1) p += __shfl_xor(p, m);
    if (dq == 0) scS[it * 16 + lq] = (mask[l] != 0) ? p * scale : -INFINITY;
  }
  __syncthreads();

  red[tid] = (tid < CROWS) ? scS[tid] : -INFINITY;
  __syncthreads();
  for (int off = 128; off > 0; off >>= 1) {
    if (tid < off) red[tid] = fmaxf(red[tid], red[tid + off]);
    __syncthreads();
  }
  const float mx = red[0];
  __syncthreads();

  float e = 0.f;
  if (tid < CROWS) {
    e = (mx == -INFINITY) ? 0.f : __expf(scS[tid] - mx);
    scS[tid] = e;
  }
  red[tid] = e;
  __syncthreads();
  for (int off = 128; off > 0; off >>= 1) {
    if (tid < off) red[tid] += red[tid + off];
    __syncthreads();
  }
  const float lsum = red[0];
  __syncthreads();

  const int lg = tid >> 6;
  const int d = tid & 63;
  float acc = 0.f;
#pragma unroll 8
  for (int it = 0; it < CROWS / 4; ++it) {
    const int ll = lg + it * 4;
    acc += scS[ll] * vh[(size_t)(l0 + ll) * HD + d];
  }
  pvS[lg][d] = acc;
  __syncthreads();

  float* rec = &part[(size_t)(h * CSPLIT + sp) * CREC];
  if (tid == 0) {
    rec[0] = mx;
    rec[1] = lsum;
  }
  if (tid < HD)
    rec[2 + tid] = pvS[0][tid] + pvS[1][tid] + pvS[2][tid] + pvS[3][tid];
}

__global__ __launch_bounds__(64) void cls_combine_kernel(
    const float* __restrict__ part, _Float16* __restrict__ joined) {
  const int h = blockIdx.x;
  const int d = threadIdx.x;

  float gmax = -INFINITY;
#pragma unroll
  for (int sp = 0; sp < CSPLIT; ++sp)
    gmax = fmaxf(gmax, part[(size_t)(h * CSPLIT + sp) * CREC]);

  float total = 0.f, acc = 0.f;
#pragma unroll
  for (int sp = 0; sp < CSPLIT; ++sp) {
    const float* rec = &part[(size_t)(h * CSPLIT + sp) * CREC];
    const float mxi = rec[0];
    const float w = (mxi == -INFINITY) ? 0.f : __expf(mxi - gmax);
    total += w * rec[1];
    acc += w * rec[2 + d];
  }
  joined[(size_t)h * HD + d] = (_Float16)(acc / total);
}

// ---------------------------------------------------------------------------
extern "C" void kernel_launch(void* const* d_in, const int* in_sizes, int n_in,
                              void* d_out, int out_size, void* d_ws,
                              size_t ws_size, hipStream_t stream) {
  const float* emb   = (const float*)d_in[0];
  const int*   mask  = (const int*)d_in[1];
  const float* W_qkv = (const float*)d_in[2];
  const float* b_qkv = (const float*)d_in[3];
  const float* W_o   = (const float*)d_in[4];
  const float* b_o   = (const float*)d_in[5];
  float* out = (float*)d_out;

  float* ws = (float*)d_ws;
  float* qkv = ws;                                    // 2048*2304 fp32
  float* qbuf = qkv + (size_t)L_SEQ * QKV_N;
  float* kbuf = qbuf + (size_t)NHEAD * L_SEQ * HD;
  float* vbuf = kbuf + (size_t)NHEAD * L_SEQ * HD;
  float* part = vbuf + (size_t)NHEAD * L_SEQ * HD;    // 12*16*66
  float* fp16pool = part + 12672;
  _Float16* A16    = (_Float16*)fp16pool;                      // 2048*768
  _Float16* Wq16T  = A16 + (size_t)L_SEQ * D_MODEL;            // 2304*768
  _Float16* Wo16T  = Wq16T + (size_t)QKV_N * D_MODEL;          // 768*768
  _Float16* J16    = (_Float16*)qkv;  // alias: qkv dead after rope_split

  cvt16_kernel<<<(L_SEQ * D_MODEL) / 1024, 256, 0, stream>>>(
      emb, A16, L_SEQ * D_MODEL);
  cvt_transpose16_kernel<<<dim3(QKV_N / 64, D_MODEL / 64), 256, 0, stream>>>(
      W_qkv, Wq16T, D_MODEL, QKV_N);
  cvt_transpose16_kernel<<<dim3(D_MODEL / 64, D_MODEL / 64), 256, 0, stream>>>(
      W_o, Wo16T, D_MODEL, D_MODEL);

  gemm16_kernel<128><<<dim3(QKV_N / 128, L_SEQ / 128), 256, 0, stream>>>(
      A16, Wq16T, b_qkv, qkv, L_SEQ, QKV_N, D_MODEL);

  rope_split_kernel<<<dim3(L_SEQ, NHEAD), 64, 0, stream>>>(qkv, qbuf, kbuf,
                                                           vbuf);

  cls_partial_kernel<<<dim3(NHEAD, CSPLIT), 256, 0, stream>>>(qbuf, kbuf, vbuf,
                                                              mask, part);

  win_attn_kernel<<<dim3(L_SEQ / TL, NHEAD), 256, 0, stream>>>(qbuf, kbuf, vbuf,
                                                               mask, J16);

  cls_combine_kernel<<<NHEAD, 64, 0, stream>>>(part, J16);

  gemm16_kernel<64><<<dim3(D_MODEL / 128, L_SEQ / 64), 256, 0, stream>>>(
      J16, Wo16T, b_o, out, L_SEQ, D_MODEL, D_MODEL);
}

// Round 7
// 168.427 us; speedup vs baseline: 3.3166x; 1.2119x over previous
//
#include <hip/hip_runtime.h>
#include <hip/hip_bf16.h>
#include <cmath>

#define D_MODEL 768
#define NHEAD 12
#define HD 64
#define L_SEQ 2048
#define WIN 128
#define QKV_N (3 * D_MODEL)

typedef _Float16 half8 __attribute__((ext_vector_type(8)));
typedef _Float16 half4v __attribute__((ext_vector_type(4)));
typedef float floatx4 __attribute__((ext_vector_type(4)));

// ---------------------------------------------------------------------------
// fp32 -> fp16 elementwise
// ---------------------------------------------------------------------------
__global__ __launch_bounds__(256) void cvt16_kernel(const float* __restrict__ In,
                                                    _Float16* __restrict__ Out,
                                                    int n) {
  const int i = (blockIdx.x * 256 + threadIdx.x) * 4;
  if (i < n) {
    const float4 v = *reinterpret_cast<const float4*>(&In[i]);
    half4v h = {(_Float16)v.x, (_Float16)v.y, (_Float16)v.z, (_Float16)v.w};
    *reinterpret_cast<half4v*>(&Out[i]) = h;
  }
}

// ---------------------------------------------------------------------------
// fp32 [R][Cn] -> fp16 transposed [Cn][R]. 64x64 LDS tile.
// ---------------------------------------------------------------------------
__global__ __launch_bounds__(256) void cvt_transpose16_kernel(
    const float* __restrict__ In, _Float16* __restrict__ Out, int R, int Cn) {
  __shared__ float tile[64][68];
  const int tid = threadIdx.x;
  const int r0 = blockIdx.y * 64;
  const int c0 = blockIdx.x * 64;
  const int tr = tid >> 4;
  const int tc4 = (tid & 15) * 4;
#pragma unroll
  for (int rr = 0; rr < 4; ++rr) {
    const int r = rr * 16 + tr;
    const float4 v =
        *reinterpret_cast<const float4*>(&In[(size_t)(r0 + r) * Cn + c0 + tc4]);
    tile[r][tc4 + 0] = v.x;
    tile[r][tc4 + 1] = v.y;
    tile[r][tc4 + 2] = v.z;
    tile[r][tc4 + 3] = v.w;
  }
  __syncthreads();
#pragma unroll
  for (int cc = 0; cc < 4; ++cc) {
    const int c = cc * 16 + tr;
    half4v h = {(_Float16)tile[tc4 + 0][c], (_Float16)tile[tc4 + 1][c],
                (_Float16)tile[tc4 + 2][c], (_Float16)tile[tc4 + 3][c]};
    *reinterpret_cast<half4v*>(&Out[(size_t)(c0 + c) * R + r0 + tc4]) = h;
  }
}

// ---------------------------------------------------------------------------
// fp16 MFMA GEMM (validated R5): C = A[M][K] @ BT[N][K]^T + bias, fp32 out.
// ---------------------------------------------------------------------------
template <int BM>
__global__ __launch_bounds__(256) void gemm16_kernel(
    const _Float16* __restrict__ A, const _Float16* __restrict__ BT,
    const float* __restrict__ bias, float* __restrict__ C, int M, int N,
    int K) {
  constexpr int BN = 128;
  constexpr int LDK = 40;
  constexpr int MF = BM / 32;

  __shared__ __align__(16) _Float16 At[BM * LDK];
  __shared__ __align__(16) _Float16 Bt[BN * LDK];

  const int tid = threadIdx.x;
  const int row0 = blockIdx.y * BM;
  const int col0 = blockIdx.x * BN;
  const int wv = tid >> 6;
  const int lane = tid & 63;
  const int wr = wv >> 1;
  const int wc = wv & 1;
  const int lrow = lane & 15;
  const int lk = lane >> 4;

  floatx4 acc[MF][4];
#pragma unroll
  for (int m = 0; m < MF; ++m)
#pragma unroll
    for (int n = 0; n < 4; ++n) acc[m][n] = (floatx4){0.f, 0.f, 0.f, 0.f};

  for (int k0 = 0; k0 < K; k0 += 32) {
#pragma unroll
    for (int c = tid; c < BM * 4; c += 256) {
      const int r = c >> 2, seg = c & 3;
      *reinterpret_cast<half8*>(&At[r * LDK + seg * 8]) =
          *reinterpret_cast<const half8*>(
              &A[(size_t)(row0 + r) * K + k0 + seg * 8]);
    }
#pragma unroll
    for (int c = tid; c < BN * 4; c += 256) {
      const int r = c >> 2, seg = c & 3;
      *reinterpret_cast<half8*>(&Bt[r * LDK + seg * 8]) =
          *reinterpret_cast<const half8*>(
              &BT[(size_t)(col0 + r) * K + k0 + seg * 8]);
    }
    __syncthreads();

    half8 af[MF], bf[4];
#pragma unroll
    for (int m = 0; m < MF; ++m)
      af[m] = *reinterpret_cast<const half8*>(
          &At[(wr * (BM / 2) + m * 16 + lrow) * LDK + lk * 8]);
#pragma unroll
    for (int n = 0; n < 4; ++n)
      bf[n] = *reinterpret_cast<const half8*>(
          &Bt[(wc * 64 + n * 16 + lrow) * LDK + lk * 8]);
#pragma unroll
    for (int m = 0; m < MF; ++m)
#pragma unroll
      for (int n = 0; n < 4; ++n)
        acc[m][n] = __builtin_amdgcn_mfma_f32_16x16x32_f16(af[m], bf[n],
                                                           acc[m][n], 0, 0, 0);
    __syncthreads();
  }

#pragma unroll
  for (int m = 0; m < MF; ++m)
#pragma unroll
    for (int n = 0; n < 4; ++n) {
      const int col = col0 + wc * 64 + n * 16 + lrow;
      const float bb = bias[col];
#pragma unroll
      for (int j = 0; j < 4; ++j) {
        const int row = row0 + wr * (BM / 2) + m * 16 + lk * 4 + j;
        C[(size_t)row * N + col] = acc[m][n][j] + bb;
      }
    }
}

// ---------------------------------------------------------------------------
// RoPE + split: now also emits fp16 copies of q,k,v for the MFMA win kernel.
// ---------------------------------------------------------------------------
__global__ __launch_bounds__(64) void rope_split_kernel(
    const float* __restrict__ qkv, float* __restrict__ q,
    float* __restrict__ k, float* __restrict__ v, _Float16* __restrict__ q16,
    _Float16* __restrict__ k16, _Float16* __restrict__ v16) {
  const int l = blockIdx.x;
  const int h = blockIdx.y;
  const int d = threadIdx.x;
  const int i = d & 31;

  const float inv = (float)(1.0 / pow(10000.0, (double)(2 * i) / 64.0));
  const float ang = (float)l * inv;
  const float c = cosf(ang);
  const float s = sinf(ang);

  const size_t base = (size_t)l * QKV_N + h * HD;
  const size_t obase = ((size_t)h * L_SEQ + l) * HD + d;

  {
    const float x = qkv[base + d];
    const float xp = qkv[base + (d ^ 32)];
    const float qv = (d < 32) ? (x * c - xp * s) : (xp * s + x * c);
    q[obase] = qv;
    q16[obase] = (_Float16)qv;
  }
  {
    const float x = qkv[base + D_MODEL + d];
    const float xp = qkv[base + D_MODEL + (d ^ 32)];
    const float kv = (d < 32) ? (x * c - xp * s) : (xp * s + x * c);
    k[obase] = kv;
    k16[obase] = (_Float16)kv;
  }
  {
    const float vv = qkv[base + 2 * D_MODEL + d];
    v[obase] = vv;
    v16[obase] = (_Float16)vv;
  }
}

// ---------------------------------------------------------------------------
// Window attention v4 — MFMA. Block = (32 q-rows, head), 256 thr = 4 waves.
// Phase 1: stage Q[32][72], K[160][72] fp16 (LDS).
// Phase 2: S[32][160] = Q K^T via mfma 16x16x32 (wave = (row-half, col-half)),
//          write masked fp32 scores to sS.
// Phase 3: stage V^T[64][168] into K's buffer; softmax per row (8-lane
//          shuffle), write normalized fp16 probs over sS (in-place alias,
//          barrier-protected).
// Phase 4: O[32][64] = P V via mfma; write fp16 joined.
// LDS ~48.7 KB -> 3 blocks/CU.
// ---------------------------------------------------------------------------
#define TL 32
#define SLOTS 160
#define LDH 72    // halfs per Q/K row (144 B, 16B-aligned, 2-way banks)
#define LDS_S 168 // floats per score row (672 B)
#define LDVT 168  // halfs per V^T row (336 B)

__global__ __launch_bounds__(256) void win_attn_kernel(
    const _Float16* __restrict__ q16, const _Float16* __restrict__ k16,
    const _Float16* __restrict__ v16, const int* __restrict__ mask,
    _Float16* __restrict__ joined) {
  const int l0 = blockIdx.x * TL;
  const int h = blockIdx.y;
  const int tid = threadIdx.x;
  const float scale = 0.036084391824351615f;  // 1/sqrt(768)

  __shared__ __align__(16) _Float16 kv16[SLOTS * LDH];  // K, then V^T (64*168<=160*72)
  __shared__ __align__(16) float sS[TL * LDS_S];        // scores; later fp16 probs
  __shared__ __align__(16) _Float16 q16l[TL * LDH];
  __shared__ float vbias[SLOTS];

  const _Float16* kh = k16 + (size_t)h * L_SEQ * HD;
  const _Float16* vh = v16 + (size_t)h * L_SEQ * HD;
  const _Float16* qh = q16 + (size_t)h * L_SEQ * HD;

  // ---- phase 1: stage Q + K ----
  {
    const int row = tid >> 3, oct = (tid & 7) * 8;  // 32x8 = 256
    *reinterpret_cast<half8*>(&q16l[row * LDH + oct]) =
        *reinterpret_cast<const half8*>(&qh[(size_t)(l0 + row) * HD + oct]);
  }
#pragma unroll
  for (int c = tid; c < SLOTS * 8; c += 256) {
    const int slot = c >> 3, oct = (c & 7) * 8;
    const int raw = l0 + slot - WIN / 2;
    const int idx = min(max(raw, 0), L_SEQ - 1);
    *reinterpret_cast<half8*>(&kv16[slot * LDH + oct]) =
        *reinterpret_cast<const half8*>(&kh[(size_t)idx * HD + oct]);
  }
  if (tid < SLOTS) {
    const int raw = l0 + tid - WIN / 2;
    const int idx = min(max(raw, 0), L_SEQ - 1);
    vbias[tid] =
        ((raw >= 0) && (raw < L_SEQ) && (mask[idx] != 0)) ? 0.f : -INFINITY;
  }
  __syncthreads();

  // ---- phase 2: MFMA scores ----
  const int wv = tid >> 6, lane = tid & 63;
  const int wr = wv >> 1, wc = wv & 1;
  const int lcol = lane & 15, loct = (lane >> 4) * 8;

  floatx4 accS[5];
#pragma unroll
  for (int f = 0; f < 5; ++f) accS[f] = (floatx4){0.f, 0.f, 0.f, 0.f};
#pragma unroll
  for (int ks = 0; ks < 2; ++ks) {
    const half8 af = *reinterpret_cast<const half8*>(
        &q16l[(wr * 16 + lcol) * LDH + ks * 32 + loct]);
#pragma unroll
    for (int f = 0; f < 5; ++f) {
      const half8 bf = *reinterpret_cast<const half8*>(
          &kv16[(wc * 80 + f * 16 + lcol) * LDH + ks * 32 + loct]);
      accS[f] =
          __builtin_amdgcn_mfma_f32_16x16x32_f16(af, bf, accS[f], 0, 0, 0);
    }
  }
#pragma unroll
  for (int f = 0; f < 5; ++f) {
    const int slot = wc * 80 + f * 16 + lcol;
    const float vb = vbias[slot];
#pragma unroll
    for (int j = 0; j < 4; ++j) {
      const int row = wr * 16 + (lane >> 4) * 4 + j;
      const bool inband = (slot >= row) && (slot <= row + WIN - 1);
      sS[row * LDS_S + slot] =
          inband ? (accS[f][j] * scale + vb) : -INFINITY;
    }
  }
  __syncthreads();

  // ---- phase 3a: stage V^T over K's buffer ----
  _Float16* vt = kv16;  // [64][LDVT]
#pragma unroll
  for (int c = tid; c < SLOTS * 8; c += 256) {
    const int slot = c >> 3, d0 = (c & 7) * 8;
    const int raw = l0 + slot - WIN / 2;
    const int idx = min(max(raw, 0), L_SEQ - 1);
    const half8 vv =
        *reinterpret_cast<const half8*>(&vh[(size_t)idx * HD + d0]);
#pragma unroll
    for (int e = 0; e < 8; ++e) vt[(d0 + e) * LDVT + slot] = vv[e];
  }

  // ---- phase 3b: softmax (thread (r=tid>>3, wg=tid&7) owns 20 slots) ----
  const int r = tid >> 3, wg = tid & 7;
  float pv[20];
  float mloc = -INFINITY;
#pragma unroll
  for (int i = 0; i < 20; ++i) {
    pv[i] = sS[r * LDS_S + wg * 20 + i];
    mloc = fmaxf(mloc, pv[i]);
  }
#pragma unroll
  for (int m = 1; m < 8; m <<= 1) mloc = fmaxf(mloc, __shfl_xor(mloc, m));
  float ssum = 0.f;
#pragma unroll
  for (int i = 0; i < 20; ++i) {
    pv[i] = __expf(pv[i] - mloc);
    ssum += pv[i];
  }
#pragma unroll
  for (int m = 1; m < 8; m <<= 1) ssum += __shfl_xor(ssum, m);
  const float rcp = 1.0f / ssum;
  __syncthreads();  // all sS reads done; vt staging done

  _Float16* pS = reinterpret_cast<_Float16*>(sS);  // [32][2*LDS_S]
#pragma unroll
  for (int i = 0; i < 20; ++i)
    pS[r * (2 * LDS_S) + wg * 20 + i] = (_Float16)(pv[i] * rcp);
  __syncthreads();

  // ---- phase 4: PV via MFMA ----
  floatx4 accO[2];
  accO[0] = (floatx4){0.f, 0.f, 0.f, 0.f};
  accO[1] = (floatx4){0.f, 0.f, 0.f, 0.f};
#pragma unroll
  for (int ks = 0; ks < 5; ++ks) {
    const half8 ap = *reinterpret_cast<const half8*>(
        &pS[(wr * 16 + lcol) * (2 * LDS_S) + ks * 32 + loct]);
#pragma unroll
    for (int cf = 0; cf < 2; ++cf) {
      const half8 bv = *reinterpret_cast<const half8*>(
          &vt[(wc * 32 + cf * 16 + lcol) * LDVT + ks * 32 + loct]);
      accO[cf] =
          __builtin_amdgcn_mfma_f32_16x16x32_f16(ap, bv, accO[cf], 0, 0, 0);
    }
  }
#pragma unroll
  for (int cf = 0; cf < 2; ++cf)
#pragma unroll
    for (int j = 0; j < 4; ++j) {
      const int row = wr * 16 + (lane >> 4) * 4 + j;
      const int d = wc * 32 + cf * 16 + lcol;
      joined[(size_t)(l0 + row) * D_MODEL + h * HD + d] =
          (_Float16)accO[cf][j];
    }
}

// ---------------------------------------------------------------------------
// CLS attention split-L (unchanged — fp32 path).
// ---------------------------------------------------------------------------
#define CSPLIT 16
#define CROWS (L_SEQ / CSPLIT)  // 128
#define CREC 66

__global__ __launch_bounds__(256) void cls_partial_kernel(
    const float* __restrict__ q, const float* __restrict__ k,
    const float* __restrict__ v, const int* __restrict__ mask,
    float* __restrict__ part) {
  const int h = blockIdx.x;
  const int sp = blockIdx.y;
  const int tid = threadIdx.x;
  const int l0 = sp * CROWS;
  const float scale = 0.036084391824351615f;

  __shared__ float scS[CROWS];
  __shared__ float red[256];
  __shared__ float pvS[4][HD];

  const float* kh = k + (size_t)h * L_SEQ * HD;
  const float* vh = v + (size_t)h * L_SEQ * HD;

  const int lq = tid >> 4;
  const int dq = tid & 15;
  const float4 q4 =
      *reinterpret_cast<const float4*>(&q[(size_t)h * L_SEQ * HD + dq * 4]);
#pragma unroll
  for (int it = 0; it < CROWS / 16; ++it) {
    const int l = l0 + it * 16 + lq;
    const float4 k4 =
        *reinterpret_cast<const float4*>(&kh[(size_t)l * HD + dq * 4]);
    float p = q4.x * k4.x + q4.y * k4.y + q4.z * k4.z + q4.w * k4.w;
#pragma unroll
    for (int m = 1; m < 16; m <<= 1) p += __shfl_xor(p, m);
    if (dq == 0) scS[it * 16 + lq] = (mask[l] != 0) ? p * scale : -INFINITY;
  }
  __syncthreads();

  red[tid] = (tid < CROWS) ? scS[tid] : -INFINITY;
  __syncthreads();
  for (int off = 128; off > 0; off >>= 1) {
    if (tid < off) red[tid] = fmaxf(red[tid], red[tid + off]);
    __syncthreads();
  }
  const float mx = red[0];
  __syncthreads();

  float e = 0.f;
  if (tid < CROWS) {
    e = (mx == -INFINITY) ? 0.f : __expf(scS[tid] - mx);
    scS[tid] = e;
  }
  red[tid] = e;
  __syncthreads();
  for (int off = 128; off > 0; off >>= 1) {
    if (tid < off) red[tid] += red[tid + off];
    __syncthreads();
  }
  const float lsum = red[0];
  __syncthreads();

  const int lg = tid >> 6;
  const int d = tid & 63;
  float acc = 0.f;
#pragma unroll 8
  for (int it = 0; it < CROWS / 4; ++it) {
    const int ll = lg + it * 4;
    acc += scS[ll] * vh[(size_t)(l0 + ll) * HD + d];
  }
  pvS[lg][d] = acc;
  __syncthreads();

  float* rec = &part[(size_t)(h * CSPLIT + sp) * CREC];
  if (tid == 0) {
    rec[0] = mx;
    rec[1] = lsum;
  }
  if (tid < HD)
    rec[2 + tid] = pvS[0][tid] + pvS[1][tid] + pvS[2][tid] + pvS[3][tid];
}

__global__ __launch_bounds__(64) void cls_combine_kernel(
    const float* __restrict__ part, _Float16* __restrict__ joined) {
  const int h = blockIdx.x;
  const int d = threadIdx.x;

  float gmax = -INFINITY;
#pragma unroll
  for (int sp = 0; sp < CSPLIT; ++sp)
    gmax = fmaxf(gmax, part[(size_t)(h * CSPLIT + sp) * CREC]);

  float total = 0.f, acc = 0.f;
#pragma unroll
  for (int sp = 0; sp < CSPLIT; ++sp) {
    const float* rec = &part[(size_t)(h * CSPLIT + sp) * CREC];
    const float mxi = rec[0];
    const float w = (mxi == -INFINITY) ? 0.f : __expf(mxi - gmax);
    total += w * rec[1];
    acc += w * rec[2 + d];
  }
  joined[(size_t)h * HD + d] = (_Float16)(acc / total);
}

// ---------------------------------------------------------------------------
extern "C" void kernel_launch(void* const* d_in, const int* in_sizes, int n_in,
                              void* d_out, int out_size, void* d_ws,
                              size_t ws_size, hipStream_t stream) {
  const float* emb   = (const float*)d_in[0];
  const int*   mask  = (const int*)d_in[1];
  const float* W_qkv = (const float*)d_in[2];
  const float* b_qkv = (const float*)d_in[3];
  const float* W_o   = (const float*)d_in[4];
  const float* b_o   = (const float*)d_in[5];
  float* out = (float*)d_out;

  float* ws = (float*)d_ws;
  float* qkv = ws;                                    // 2048*2304 fp32
  float* qbuf = qkv + (size_t)L_SEQ * QKV_N;
  float* kbuf = qbuf + (size_t)NHEAD * L_SEQ * HD;
  float* vbuf = kbuf + (size_t)NHEAD * L_SEQ * HD;
  float* part = vbuf + (size_t)NHEAD * L_SEQ * HD;    // 12*16*66
  float* fp16pool = part + 12672;
  _Float16* A16    = (_Float16*)fp16pool;                      // 2048*768
  _Float16* Wq16T  = A16 + (size_t)L_SEQ * D_MODEL;            // 2304*768
  _Float16* Wo16T  = Wq16T + (size_t)QKV_N * D_MODEL;          // 768*768
  _Float16* q16    = Wo16T + (size_t)D_MODEL * D_MODEL;        // 12*2048*64
  _Float16* k16    = q16 + (size_t)NHEAD * L_SEQ * HD;
  _Float16* v16    = k16 + (size_t)NHEAD * L_SEQ * HD;
  _Float16* J16    = (_Float16*)qkv;  // alias: qkv dead after rope_split

  cvt16_kernel<<<(L_SEQ * D_MODEL) / 1024, 256, 0, stream>>>(
      emb, A16, L_SEQ * D_MODEL);
  cvt_transpose16_kernel<<<dim3(QKV_N / 64, D_MODEL / 64), 256, 0, stream>>>(
      W_qkv, Wq16T, D_MODEL, QKV_N);
  cvt_transpose16_kernel<<<dim3(D_MODEL / 64, D_MODEL / 64), 256, 0, stream>>>(
      W_o, Wo16T, D_MODEL, D_MODEL);

  gemm16_kernel<128><<<dim3(QKV_N / 128, L_SEQ / 128), 256, 0, stream>>>(
      A16, Wq16T, b_qkv, qkv, L_SEQ, QKV_N, D_MODEL);

  rope_split_kernel<<<dim3(L_SEQ, NHEAD), 64, 0, stream>>>(
      qkv, qbuf, kbuf, vbuf, q16, k16, v16);

  cls_partial_kernel<<<dim3(NHEAD, CSPLIT), 256, 0, stream>>>(qbuf, kbuf, vbuf,
                                                              mask, part);

  win_attn_kernel<<<dim3(L_SEQ / TL, NHEAD), 256, 0, stream>>>(
      q16, k16, v16, mask, J16);

  cls_combine_kernel<<<NHEAD, 64, 0, stream>>>(part, J16);

  gemm16_kernel<64><<<dim3(D_MODEL / 128, L_SEQ / 64), 256, 0, stream>>>(
      J16, Wo16T, b_o, out, L_SEQ, D_MODEL, D_MODEL);
}

// Round 8
// 158.309 us; speedup vs baseline: 3.5286x; 1.0639x over previous
//
#include <hip/hip_runtime.h>
#include <hip/hip_bf16.h>
#include <cmath>

#define D_MODEL 768
#define NHEAD 12
#define HD 64
#define L_SEQ 2048
#define WIN 128
#define QKV_N (3 * D_MODEL)

typedef _Float16 half8 __attribute__((ext_vector_type(8)));
typedef _Float16 half4v __attribute__((ext_vector_type(4)));
typedef float floatx4 __attribute__((ext_vector_type(4)));

// ---------------------------------------------------------------------------
// fp32 -> fp16 elementwise
// ---------------------------------------------------------------------------
__global__ __launch_bounds__(256) void cvt16_kernel(const float* __restrict__ In,
                                                    _Float16* __restrict__ Out,
                                                    int n) {
  const int i = (blockIdx.x * 256 + threadIdx.x) * 4;
  if (i < n) {
    const float4 v = *reinterpret_cast<const float4*>(&In[i]);
    half4v h = {(_Float16)v.x, (_Float16)v.y, (_Float16)v.z, (_Float16)v.w};
    *reinterpret_cast<half4v*>(&Out[i]) = h;
  }
}

// ---------------------------------------------------------------------------
// fp32 [R][Cn] -> fp16 transposed [Cn][R]. 64x64 LDS tile.
// ---------------------------------------------------------------------------
__global__ __launch_bounds__(256) void cvt_transpose16_kernel(
    const float* __restrict__ In, _Float16* __restrict__ Out, int R, int Cn) {
  __shared__ float tile[64][68];
  const int tid = threadIdx.x;
  const int r0 = blockIdx.y * 64;
  const int c0 = blockIdx.x * 64;
  const int tr = tid >> 4;
  const int tc4 = (tid & 15) * 4;
#pragma unroll
  for (int rr = 0; rr < 4; ++rr) {
    const int r = rr * 16 + tr;
    const float4 v =
        *reinterpret_cast<const float4*>(&In[(size_t)(r0 + r) * Cn + c0 + tc4]);
    tile[r][tc4 + 0] = v.x;
    tile[r][tc4 + 1] = v.y;
    tile[r][tc4 + 2] = v.z;
    tile[r][tc4 + 3] = v.w;
  }
  __syncthreads();
#pragma unroll
  for (int cc = 0; cc < 4; ++cc) {
    const int c = cc * 16 + tr;
    half4v h = {(_Float16)tile[tc4 + 0][c], (_Float16)tile[tc4 + 1][c],
                (_Float16)tile[tc4 + 2][c], (_Float16)tile[tc4 + 3][c]};
    *reinterpret_cast<half4v*>(&Out[(size_t)(c0 + c) * R + r0 + tc4]) = h;
  }
}

// ---------------------------------------------------------------------------
// fp16 MFMA GEMM (validated R5): C = A[M][K] @ BT[N][K]^T + bias.
// OutT = _Float16 (QKV) or float (final projection).
// ---------------------------------------------------------------------------
template <int BM, typename OutT>
__global__ __launch_bounds__(256) void gemm16_kernel(
    const _Float16* __restrict__ A, const _Float16* __restrict__ BT,
    const float* __restrict__ bias, OutT* __restrict__ C, int M, int N,
    int K) {
  constexpr int BN = 128;
  constexpr int LDK = 40;
  constexpr int MF = BM / 32;

  __shared__ __align__(16) _Float16 At[BM * LDK];
  __shared__ __align__(16) _Float16 Bt[BN * LDK];

  const int tid = threadIdx.x;
  const int row0 = blockIdx.y * BM;
  const int col0 = blockIdx.x * BN;
  const int wv = tid >> 6;
  const int lane = tid & 63;
  const int wr = wv >> 1;
  const int wc = wv & 1;
  const int lrow = lane & 15;
  const int lk = lane >> 4;

  floatx4 acc[MF][4];
#pragma unroll
  for (int m = 0; m < MF; ++m)
#pragma unroll
    for (int n = 0; n < 4; ++n) acc[m][n] = (floatx4){0.f, 0.f, 0.f, 0.f};

  for (int k0 = 0; k0 < K; k0 += 32) {
#pragma unroll
    for (int c = tid; c < BM * 4; c += 256) {
      const int r = c >> 2, seg = c & 3;
      *reinterpret_cast<half8*>(&At[r * LDK + seg * 8]) =
          *reinterpret_cast<const half8*>(
              &A[(size_t)(row0 + r) * K + k0 + seg * 8]);
    }
#pragma unroll
    for (int c = tid; c < BN * 4; c += 256) {
      const int r = c >> 2, seg = c & 3;
      *reinterpret_cast<half8*>(&Bt[r * LDK + seg * 8]) =
          *reinterpret_cast<const half8*>(
              &BT[(size_t)(col0 + r) * K + k0 + seg * 8]);
    }
    __syncthreads();

    half8 af[MF], bf[4];
#pragma unroll
    for (int m = 0; m < MF; ++m)
      af[m] = *reinterpret_cast<const half8*>(
          &At[(wr * (BM / 2) + m * 16 + lrow) * LDK + lk * 8]);
#pragma unroll
    for (int n = 0; n < 4; ++n)
      bf[n] = *reinterpret_cast<const half8*>(
          &Bt[(wc * 64 + n * 16 + lrow) * LDK + lk * 8]);
#pragma unroll
    for (int m = 0; m < MF; ++m)
#pragma unroll
      for (int n = 0; n < 4; ++n)
        acc[m][n] = __builtin_amdgcn_mfma_f32_16x16x32_f16(af[m], bf[n],
                                                           acc[m][n], 0, 0, 0);
    __syncthreads();
  }

#pragma unroll
  for (int m = 0; m < MF; ++m)
#pragma unroll
    for (int n = 0; n < 4; ++n) {
      const int col = col0 + wc * 64 + n * 16 + lrow;
      const float bb = bias[col];
#pragma unroll
      for (int j = 0; j < 4; ++j) {
        const int row = row0 + wr * (BM / 2) + m * 16 + lk * 4 + j;
        C[(size_t)row * N + col] = (OutT)(acc[m][n][j] + bb);
      }
    }
}

// ---------------------------------------------------------------------------
// RoPE + split v2 — fp16 in/out, no doubles, no fp32 path.
// Block = one l (256 threads, 3 cols each); emits q16/k16/v16 [H][L][64].
// ---------------------------------------------------------------------------
__global__ __launch_bounds__(256) void rope_split_kernel(
    const _Float16* __restrict__ qkv16, _Float16* __restrict__ q16,
    _Float16* __restrict__ k16, _Float16* __restrict__ v16) {
  const int l = blockIdx.x;
  const int t = threadIdx.x;
  const float lf = (float)l;
  const size_t rbase = (size_t)l * QKV_N;

#pragma unroll
  for (int j = 0; j < 3; ++j) {
    const int c = t + j * 256;  // 0..767
    const int h = c >> 6, d = c & 63, i = d & 31;
    // inv_freq = 10000^(-2i/64) = exp2(-i * (2/64)*log2(10000))
    const float inv = exp2f(-0.4152410118609203f * (float)i);
    float sn, cs;
    sincosf(lf * inv, &sn, &cs);

    const size_t obase = ((size_t)h * L_SEQ + l) * HD + d;
    const size_t cbase = rbase + h * HD;

    const float xq = (float)qkv16[cbase + d];
    const float xqp = (float)qkv16[cbase + (d ^ 32)];
    q16[obase] =
        (_Float16)((d < 32) ? (xq * cs - xqp * sn) : (xqp * sn + xq * cs));

    const float xk = (float)qkv16[cbase + D_MODEL + d];
    const float xkp = (float)qkv16[cbase + D_MODEL + (d ^ 32)];
    k16[obase] =
        (_Float16)((d < 32) ? (xk * cs - xkp * sn) : (xkp * sn + xk * cs));

    v16[obase] = qkv16[cbase + 2 * D_MODEL + d];
  }
}

// ---------------------------------------------------------------------------
// Window attention v4 — MFMA (unchanged from R7, validated).
// ---------------------------------------------------------------------------
#define TL 32
#define SLOTS 160
#define LDH 72
#define LDS_S 168
#define LDVT 168

__global__ __launch_bounds__(256) void win_attn_kernel(
    const _Float16* __restrict__ q16, const _Float16* __restrict__ k16,
    const _Float16* __restrict__ v16, const int* __restrict__ mask,
    _Float16* __restrict__ joined) {
  const int l0 = blockIdx.x * TL;
  const int h = blockIdx.y;
  const int tid = threadIdx.x;
  const float scale = 0.036084391824351615f;  // 1/sqrt(768)

  __shared__ __align__(16) _Float16 kv16[SLOTS * LDH];
  __shared__ __align__(16) float sS[TL * LDS_S];
  __shared__ __align__(16) _Float16 q16l[TL * LDH];
  __shared__ float vbias[SLOTS];

  const _Float16* kh = k16 + (size_t)h * L_SEQ * HD;
  const _Float16* vh = v16 + (size_t)h * L_SEQ * HD;
  const _Float16* qh = q16 + (size_t)h * L_SEQ * HD;

  {
    const int row = tid >> 3, oct = (tid & 7) * 8;
    *reinterpret_cast<half8*>(&q16l[row * LDH + oct]) =
        *reinterpret_cast<const half8*>(&qh[(size_t)(l0 + row) * HD + oct]);
  }
#pragma unroll
  for (int c = tid; c < SLOTS * 8; c += 256) {
    const int slot = c >> 3, oct = (c & 7) * 8;
    const int raw = l0 + slot - WIN / 2;
    const int idx = min(max(raw, 0), L_SEQ - 1);
    *reinterpret_cast<half8*>(&kv16[slot * LDH + oct]) =
        *reinterpret_cast<const half8*>(&kh[(size_t)idx * HD + oct]);
  }
  if (tid < SLOTS) {
    const int raw = l0 + tid - WIN / 2;
    const int idx = min(max(raw, 0), L_SEQ - 1);
    vbias[tid] =
        ((raw >= 0) && (raw < L_SEQ) && (mask[idx] != 0)) ? 0.f : -INFINITY;
  }
  __syncthreads();

  const int wv = tid >> 6, lane = tid & 63;
  const int wr = wv >> 1, wc = wv & 1;
  const int lcol = lane & 15, loct = (lane >> 4) * 8;

  floatx4 accS[5];
#pragma unroll
  for (int f = 0; f < 5; ++f) accS[f] = (floatx4){0.f, 0.f, 0.f, 0.f};
#pragma unroll
  for (int ks = 0; ks < 2; ++ks) {
    const half8 af = *reinterpret_cast<const half8*>(
        &q16l[(wr * 16 + lcol) * LDH + ks * 32 + loct]);
#pragma unroll
    for (int f = 0; f < 5; ++f) {
      const half8 bf = *reinterpret_cast<const half8*>(
          &kv16[(wc * 80 + f * 16 + lcol) * LDH + ks * 32 + loct]);
      accS[f] =
          __builtin_amdgcn_mfma_f32_16x16x32_f16(af, bf, accS[f], 0, 0, 0);
    }
  }
#pragma unroll
  for (int f = 0; f < 5; ++f) {
    const int slot = wc * 80 + f * 16 + lcol;
    const float vb = vbias[slot];
#pragma unroll
    for (int j = 0; j < 4; ++j) {
      const int row = wr * 16 + (lane >> 4) * 4 + j;
      const bool inband = (slot >= row) && (slot <= row + WIN - 1);
      sS[row * LDS_S + slot] = inband ? (accS[f][j] * scale + vb) : -INFINITY;
    }
  }
  __syncthreads();

  _Float16* vt = kv16;
#pragma unroll
  for (int c = tid; c < SLOTS * 8; c += 256) {
    const int slot = c >> 3, d0 = (c & 7) * 8;
    const int raw = l0 + slot - WIN / 2;
    const int idx = min(max(raw, 0), L_SEQ - 1);
    const half8 vv =
        *reinterpret_cast<const half8*>(&vh[(size_t)idx * HD + d0]);
#pragma unroll
    for (int e = 0; e < 8; ++e) vt[(d0 + e) * LDVT + slot] = vv[e];
  }

  const int r = tid >> 3, wg = tid & 7;
  float pv[20];
  float mloc = -INFINITY;
#pragma unroll
  for (int i = 0; i < 20; ++i) {
    pv[i] = sS[r * LDS_S + wg * 20 + i];
    mloc = fmaxf(mloc, pv[i]);
  }
#pragma unroll
  for (int m = 1; m < 8; m <<= 1) mloc = fmaxf(mloc, __shfl_xor(mloc, m));
  float ssum = 0.f;
#pragma unroll
  for (int i = 0; i < 20; ++i) {
    pv[i] = __expf(pv[i] - mloc);
    ssum += pv[i];
  }
#pragma unroll
  for (int m = 1; m < 8; m <<= 1) ssum += __shfl_xor(ssum, m);
  const float rcp = 1.0f / ssum;
  __syncthreads();

  _Float16* pS = reinterpret_cast<_Float16*>(sS);
#pragma unroll
  for (int i = 0; i < 20; ++i)
    pS[r * (2 * LDS_S) + wg * 20 + i] = (_Float16)(pv[i] * rcp);
  __syncthreads();

  floatx4 accO[2];
  accO[0] = (floatx4){0.f, 0.f, 0.f, 0.f};
  accO[1] = (floatx4){0.f, 0.f, 0.f, 0.f};
#pragma unroll
  for (int ks = 0; ks < 5; ++ks) {
    const half8 ap = *reinterpret_cast<const half8*>(
        &pS[(wr * 16 + lcol) * (2 * LDS_S) + ks * 32 + loct]);
#pragma unroll
    for (int cf = 0; cf < 2; ++cf) {
      const half8 bv = *reinterpret_cast<const half8*>(
          &vt[(wc * 32 + cf * 16 + lcol) * LDVT + ks * 32 + loct]);
      accO[cf] =
          __builtin_amdgcn_mfma_f32_16x16x32_f16(ap, bv, accO[cf], 0, 0, 0);
    }
  }
#pragma unroll
  for (int cf = 0; cf < 2; ++cf)
#pragma unroll
    for (int j = 0; j < 4; ++j) {
      const int row = wr * 16 + (lane >> 4) * 4 + j;
      const int d = wc * 32 + cf * 16 + lcol;
      joined[(size_t)(l0 + row) * D_MODEL + h * HD + d] =
          (_Float16)accO[cf][j];
    }
}

// ---------------------------------------------------------------------------
// CLS attention split-L — fp16 inputs, fp32 accumulation.
// ---------------------------------------------------------------------------
#define CSPLIT 16
#define CROWS (L_SEQ / CSPLIT)  // 128
#define CREC 66

__global__ __launch_bounds__(256) void cls_partial_kernel(
    const _Float16* __restrict__ q16, const _Float16* __restrict__ k16,
    const _Float16* __restrict__ v16, const int* __restrict__ mask,
    float* __restrict__ part) {
  const int h = blockIdx.x;
  const int sp = blockIdx.y;
  const int tid = threadIdx.x;
  const int l0 = sp * CROWS;
  const float scale = 0.036084391824351615f;

  __shared__ float scS[CROWS];
  __shared__ float red[256];
  __shared__ float pvS[4][HD];

  const _Float16* kh = k16 + (size_t)h * L_SEQ * HD;
  const _Float16* vh = v16 + (size_t)h * L_SEQ * HD;

  const int lq = tid >> 4;
  const int dq = tid & 15;
  const half4v q4 =
      *reinterpret_cast<const half4v*>(&q16[(size_t)h * L_SEQ * HD + dq * 4]);
#pragma unroll
  for (int it = 0; it < CROWS / 16; ++it) {
    const int l = l0 + it * 16 + lq;
    const half4v k4 =
        *reinterpret_cast<const half4v*>(&kh[(size_t)l * HD + dq * 4]);
    float p = (float)q4[0] * (float)k4[0] + (float)q4[1] * (float)k4[1] +
              (float)q4[2] * (float)k4[2] + (float)q4[3] * (float)k4[3];
#pragma unroll
    for (int m = 1; m < 16; m <<= 1) p += __shfl_xor(p, m);
    if (dq == 0) scS[it * 16 + lq] = (mask[l] != 0) ? p * scale : -INFINITY;
  }
  __syncthreads();

  red[tid] = (tid < CROWS) ? scS[tid] : -INFINITY;
  __syncthreads();
  for (int off = 128; off > 0; off >>= 1) {
    if (tid < off) red[tid] = fmaxf(red[tid], red[tid + off]);
    __syncthreads();
  }
  const float mx = red[0];
  __syncthreads();

  float e = 0.f;
  if (tid < CROWS) {
    e = (mx == -INFINITY) ? 0.f : __expf(scS[tid] - mx);
    scS[tid] = e;
  }
  red[tid] = e;
  __syncthreads();
  for (int off = 128; off > 0; off >>= 1) {
    if (tid < off) red[tid] += red[tid + off];
    __syncthreads();
  }
  const float lsum = red[0];
  __syncthreads();

  const int lg = tid >> 6;
  const int d = tid & 63;
  float acc = 0.f;
#pragma unroll 8
  for (int it = 0; it < CROWS / 4; ++it) {
    const int ll = lg + it * 4;
    acc += scS[ll] * (float)vh[(size_t)(l0 + ll) * HD + d];
  }
  pvS[lg][d] = acc;
  __syncthreads();

  float* rec = &part[(size_t)(h * CSPLIT + sp) * CREC];
  if (tid == 0) {
    rec[0] = mx;
    rec[1] = lsum;
  }
  if (tid < HD)
    rec[2 + tid] = pvS[0][tid] + pvS[1][tid] + pvS[2][tid] + pvS[3][tid];
}

__global__ __launch_bounds__(64) void cls_combine_kernel(
    const float* __restrict__ part, _Float16* __restrict__ joined) {
  const int h = blockIdx.x;
  const int d = threadIdx.x;

  float gmax = -INFINITY;
#pragma unroll
  for (int sp = 0; sp < CSPLIT; ++sp)
    gmax = fmaxf(gmax, part[(size_t)(h * CSPLIT + sp) * CREC]);

  float total = 0.f, acc = 0.f;
#pragma unroll
  for (int sp = 0; sp < CSPLIT; ++sp) {
    const float* rec = &part[(size_t)(h * CSPLIT + sp) * CREC];
    const float mxi = rec[0];
    const float w = (mxi == -INFINITY) ? 0.f : __expf(mxi - gmax);
    total += w * rec[1];
    acc += w * rec[2 + d];
  }
  joined[(size_t)h * HD + d] = (_Float16)(acc / total);
}

// ---------------------------------------------------------------------------
extern "C" void kernel_launch(void* const* d_in, const int* in_sizes, int n_in,
                              void* d_out, int out_size, void* d_ws,
                              size_t ws_size, hipStream_t stream) {
  const float* emb   = (const float*)d_in[0];
  const int*   mask  = (const int*)d_in[1];
  const float* W_qkv = (const float*)d_in[2];
  const float* b_qkv = (const float*)d_in[3];
  const float* W_o   = (const float*)d_in[4];
  const float* b_o   = (const float*)d_in[5];
  float* out = (float*)d_out;

  _Float16* hp = (_Float16*)d_ws;
  _Float16* qkv16 = hp;                                      // 2048*2304
  _Float16* A16   = qkv16 + (size_t)L_SEQ * QKV_N;           // 2048*768
  _Float16* Wq16T = A16 + (size_t)L_SEQ * D_MODEL;           // 2304*768
  _Float16* Wo16T = Wq16T + (size_t)QKV_N * D_MODEL;         // 768*768
  _Float16* q16   = Wo16T + (size_t)D_MODEL * D_MODEL;       // 12*2048*64
  _Float16* k16   = q16 + (size_t)NHEAD * L_SEQ * HD;
  _Float16* v16   = k16 + (size_t)NHEAD * L_SEQ * HD;
  float*    part  = (float*)(v16 + (size_t)NHEAD * L_SEQ * HD);  // 12*16*66
  _Float16* J16   = qkv16;  // alias: qkv16 dead after rope_split

  cvt16_kernel<<<(L_SEQ * D_MODEL) / 1024, 256, 0, stream>>>(
      emb, A16, L_SEQ * D_MODEL);
  cvt_transpose16_kernel<<<dim3(QKV_N / 64, D_MODEL / 64), 256, 0, stream>>>(
      W_qkv, Wq16T, D_MODEL, QKV_N);
  cvt_transpose16_kernel<<<dim3(D_MODEL / 64, D_MODEL / 64), 256, 0, stream>>>(
      W_o, Wo16T, D_MODEL, D_MODEL);

  gemm16_kernel<128, _Float16>
      <<<dim3(QKV_N / 128, L_SEQ / 128), 256, 0, stream>>>(
          A16, Wq16T, b_qkv, qkv16, L_SEQ, QKV_N, D_MODEL);

  rope_split_kernel<<<L_SEQ, 256, 0, stream>>>(qkv16, q16, k16, v16);

  cls_partial_kernel<<<dim3(NHEAD, CSPLIT), 256, 0, stream>>>(q16, k16, v16,
                                                              mask, part);

  win_attn_kernel<<<dim3(L_SEQ / TL, NHEAD), 256, 0, stream>>>(q16, k16, v16,
                                                               mask, J16);

  cls_combine_kernel<<<NHEAD, 64, 0, stream>>>(part, J16);

  gemm16_kernel<64, float><<<dim3(D_MODEL / 128, L_SEQ / 64), 256, 0, stream>>>(
      J16, Wo16T, b_o, out, L_SEQ, D_MODEL, D_MODEL);
}

// Round 9
// 130.820 us; speedup vs baseline: 4.2701x; 1.2101x over previous
//
#include <hip/hip_runtime.h>
#include <hip/hip_bf16.h>
#include <cmath>

#define D_MODEL 768
#define NHEAD 12
#define HD 64
#define L_SEQ 2048
#define WIN 128
#define QKV_N (3 * D_MODEL)

typedef _Float16 half8 __attribute__((ext_vector_type(8)));
typedef _Float16 half4v __attribute__((ext_vector_type(4)));
typedef float floatx4 __attribute__((ext_vector_type(4)));

// ---------------------------------------------------------------------------
// fp32 -> fp16 elementwise
// ---------------------------------------------------------------------------
__global__ __launch_bounds__(256) void cvt16_kernel(const float* __restrict__ In,
                                                    _Float16* __restrict__ Out,
                                                    int n) {
  const int i = (blockIdx.x * 256 + threadIdx.x) * 4;
  if (i < n) {
    const float4 v = *reinterpret_cast<const float4*>(&In[i]);
    half4v h = {(_Float16)v.x, (_Float16)v.y, (_Float16)v.z, (_Float16)v.w};
    *reinterpret_cast<half4v*>(&Out[i]) = h;
  }
}

// ---------------------------------------------------------------------------
// fp32 [R][Cn] -> fp16 transposed [Cn][R]. 64x64 LDS tile.
// ---------------------------------------------------------------------------
__global__ __launch_bounds__(256) void cvt_transpose16_kernel(
    const float* __restrict__ In, _Float16* __restrict__ Out, int R, int Cn) {
  __shared__ float tile[64][68];
  const int tid = threadIdx.x;
  const int r0 = blockIdx.y * 64;
  const int c0 = blockIdx.x * 64;
  const int tr = tid >> 4;
  const int tc4 = (tid & 15) * 4;
#pragma unroll
  for (int rr = 0; rr < 4; ++rr) {
    const int r = rr * 16 + tr;
    const float4 v =
        *reinterpret_cast<const float4*>(&In[(size_t)(r0 + r) * Cn + c0 + tc4]);
    tile[r][tc4 + 0] = v.x;
    tile[r][tc4 + 1] = v.y;
    tile[r][tc4 + 2] = v.z;
    tile[r][tc4 + 3] = v.w;
  }
  __syncthreads();
#pragma unroll
  for (int cc = 0; cc < 4; ++cc) {
    const int c = cc * 16 + tr;
    half4v h = {(_Float16)tile[tc4 + 0][c], (_Float16)tile[tc4 + 1][c],
                (_Float16)tile[tc4 + 2][c], (_Float16)tile[tc4 + 3][c]};
    *reinterpret_cast<half4v*>(&Out[(size_t)(c0 + c) * R + r0 + tc4]) = h;
  }
}

// ---------------------------------------------------------------------------
// fp16 MFMA GEMM v2: reg-staged 2-phase pipeline (loads for tile t+1 issued
// before MFMA on tile t). Optional fused RoPE+split epilogue (ROPE=true,
// requires BN=128): writes q16/k16/v16 [H][L][64] directly with rotation.
// C/D layout (m89-verified): col = lane&15, row = (lane>>4)*4 + j.
// ---------------------------------------------------------------------------
template <int BM, int BN, typename OutT, bool ROPE>
__global__ __launch_bounds__(256) void gemm16_kernel(
    const _Float16* __restrict__ A, const _Float16* __restrict__ BT,
    const float* __restrict__ bias, OutT* __restrict__ C,
    _Float16* __restrict__ q16, _Float16* __restrict__ k16,
    _Float16* __restrict__ v16, int M, int N, int K) {
  constexpr int LDK = 40;      // padded LDS row (80 B) — conflict-free b128 reads
  constexpr int MF = BM / 32;  // m-fragments per wave
  constexpr int NF = BN / 32;  // n-fragments per wave
  constexpr int CA = BM * 4 / 256;  // A half8-chunks per thread
  constexpr int CB = BN * 4 / 256;  // B half8-chunks per thread

  __shared__ __align__(16) _Float16 At[BM * LDK];
  __shared__ __align__(16) _Float16 Bt[BN * LDK];

  const int tid = threadIdx.x;
  const int row0 = blockIdx.y * BM;
  const int col0 = blockIdx.x * BN;
  const int wv = tid >> 6;
  const int lane = tid & 63;
  const int wr = wv >> 1;
  const int wc = wv & 1;
  const int lrow = lane & 15;
  const int lk = lane >> 4;

  floatx4 acc[MF][NF];
#pragma unroll
  for (int m = 0; m < MF; ++m)
#pragma unroll
    for (int n = 0; n < NF; ++n) acc[m][n] = (floatx4){0.f, 0.f, 0.f, 0.f};

  half8 aR[CA], bR[CB];
  const int nt = K / 32;

  // prologue: load tile 0 into regs
#pragma unroll
  for (int i = 0; i < CA; ++i) {
    const int c = tid + i * 256, r = c >> 2, seg = c & 3;
    aR[i] = *reinterpret_cast<const half8*>(&A[(size_t)(row0 + r) * K + seg * 8]);
  }
#pragma unroll
  for (int i = 0; i < CB; ++i) {
    const int c = tid + i * 256, r = c >> 2, seg = c & 3;
    bR[i] =
        *reinterpret_cast<const half8*>(&BT[(size_t)(col0 + r) * K + seg * 8]);
  }

  for (int t = 0; t < nt; ++t) {
    if (t) __syncthreads();  // tile t-1 consumers done; LDS reusable
#pragma unroll
    for (int i = 0; i < CA; ++i) {
      const int c = tid + i * 256, r = c >> 2, seg = c & 3;
      *reinterpret_cast<half8*>(&At[r * LDK + seg * 8]) = aR[i];
    }
#pragma unroll
    for (int i = 0; i < CB; ++i) {
      const int c = tid + i * 256, r = c >> 2, seg = c & 3;
      *reinterpret_cast<half8*>(&Bt[r * LDK + seg * 8]) = bR[i];
    }
    __syncthreads();

    if (t + 1 < nt) {  // issue next-tile loads; latency hides under MFMA below
      const int k0 = (t + 1) * 32;
#pragma unroll
      for (int i = 0; i < CA; ++i) {
        const int c = tid + i * 256, r = c >> 2, seg = c & 3;
        aR[i] = *reinterpret_cast<const half8*>(
            &A[(size_t)(row0 + r) * K + k0 + seg * 8]);
      }
#pragma unroll
      for (int i = 0; i < CB; ++i) {
        const int c = tid + i * 256, r = c >> 2, seg = c & 3;
        bR[i] = *reinterpret_cast<const half8*>(
            &BT[(size_t)(col0 + r) * K + k0 + seg * 8]);
      }
    }

    half8 af[MF], bf[NF];
#pragma unroll
    for (int m = 0; m < MF; ++m)
      af[m] = *reinterpret_cast<const half8*>(
          &At[(wr * (BM / 2) + m * 16 + lrow) * LDK + lk * 8]);
#pragma unroll
    for (int n = 0; n < NF; ++n)
      bf[n] = *reinterpret_cast<const half8*>(
          &Bt[(wc * (BN / 2) + n * 16 + lrow) * LDK + lk * 8]);
#pragma unroll
    for (int m = 0; m < MF; ++m)
#pragma unroll
      for (int n = 0; n < NF; ++n)
        acc[m][n] = __builtin_amdgcn_mfma_f32_16x16x32_f16(af[m], bf[n],
                                                           acc[m][n], 0, 0, 0);
  }

  if constexpr (!ROPE) {
#pragma unroll
    for (int m = 0; m < MF; ++m)
#pragma unroll
      for (int n = 0; n < NF; ++n) {
        const int col = col0 + wc * (BN / 2) + n * 16 + lrow;
        const float bb = bias[col];
#pragma unroll
        for (int j = 0; j < 4; ++j) {
          const int row = row0 + wr * (BM / 2) + m * 16 + lk * 4 + j;
          C[(size_t)row * N + col] = (OutT)(acc[m][n][j] + bb);
        }
      }
  } else {
    // BN=128: block is wholly inside q, k, or v (768 = 6*128).
    const int part = col0 / D_MODEL;                     // 0=q 1=k 2=v
    const int h = ((col0 % D_MODEL) >> 6) + wc;          // head
    _Float16* dst = (part == 0) ? q16 : (part == 1) ? k16 : v16;
    // bias per n (col = col0 + wc*64 + n*16 + lrow)
    float bb[4];
#pragma unroll
    for (int n = 0; n < 4; ++n) bb[n] = bias[col0 + wc * 64 + n * 16 + lrow];
    // inv_freq for i = lrow (n even) and i = 16+lrow (n odd)
    const float inv0 = exp2f(-0.4152410118609203f * (float)lrow);
    const float inv1 = inv0 * 0.01f;  // *10000^(-32/64)
#pragma unroll
    for (int m = 0; m < MF; ++m)
#pragma unroll
      for (int j = 0; j < 4; ++j) {
        const int l = row0 + wr * (BM / 2) + m * 16 + lk * 4 + j;
        float val[4];
#pragma unroll
        for (int n = 0; n < 4; ++n) val[n] = acc[m][n][j] + bb[n];
        float o[4];
        if (part < 2) {
          float sn0, cs0, sn1, cs1;
          __sincosf((float)l * inv0, &sn0, &cs0);
          __sincosf((float)l * inv1, &sn1, &cs1);
          o[0] = val[0] * cs0 - val[2] * sn0;
          o[1] = val[1] * cs1 - val[3] * sn1;
          o[2] = val[0] * sn0 + val[2] * cs0;
          o[3] = val[1] * sn1 + val[3] * cs1;
        } else {
          o[0] = val[0]; o[1] = val[1]; o[2] = val[2]; o[3] = val[3];
        }
        const size_t base = ((size_t)h * L_SEQ + l) * HD + lrow;
#pragma unroll
        for (int n = 0; n < 4; ++n) dst[base + n * 16] = (_Float16)o[n];
      }
  }
}

// ---------------------------------------------------------------------------
// Window attention v4 — MFMA (unchanged from R7, validated).
// ---------------------------------------------------------------------------
#define TL 32
#define SLOTS 160
#define LDH 72
#define LDS_S 168
#define LDVT 168

__global__ __launch_bounds__(256) void win_attn_kernel(
    const _Float16* __restrict__ q16, const _Float16* __restrict__ k16,
    const _Float16* __restrict__ v16, const int* __restrict__ mask,
    _Float16* __restrict__ joined) {
  const int l0 = blockIdx.x * TL;
  const int h = blockIdx.y;
  const int tid = threadIdx.x;
  const float scale = 0.036084391824351615f;  // 1/sqrt(768)

  __shared__ __align__(16) _Float16 kv16[SLOTS * LDH];
  __shared__ __align__(16) float sS[TL * LDS_S];
  __shared__ __align__(16) _Float16 q16l[TL * LDH];
  __shared__ float vbias[SLOTS];

  const _Float16* kh = k16 + (size_t)h * L_SEQ * HD;
  const _Float16* vh = v16 + (size_t)h * L_SEQ * HD;
  const _Float16* qh = q16 + (size_t)h * L_SEQ * HD;

  {
    const int row = tid >> 3, oct = (tid & 7) * 8;
    *reinterpret_cast<half8*>(&q16l[row * LDH + oct]) =
        *reinterpret_cast<const half8*>(&qh[(size_t)(l0 + row) * HD + oct]);
  }
#pragma unroll
  for (int c = tid; c < SLOTS * 8; c += 256) {
    const int slot = c >> 3, oct = (c & 7) * 8;
    const int raw = l0 + slot - WIN / 2;
    const int idx = min(max(raw, 0), L_SEQ - 1);
    *reinterpret_cast<half8*>(&kv16[slot * LDH + oct]) =
        *reinterpret_cast<const half8*>(&kh[(size_t)idx * HD + oct]);
  }
  if (tid < SLOTS) {
    const int raw = l0 + tid - WIN / 2;
    const int idx = min(max(raw, 0), L_SEQ - 1);
    vbias[tid] =
        ((raw >= 0) && (raw < L_SEQ) && (mask[idx] != 0)) ? 0.f : -INFINITY;
  }
  __syncthreads();

  const int wv = tid >> 6, lane = tid & 63;
  const int wr = wv >> 1, wc = wv & 1;
  const int lcol = lane & 15, loct = (lane >> 4) * 8;

  floatx4 accS[5];
#pragma unroll
  for (int f = 0; f < 5; ++f) accS[f] = (floatx4){0.f, 0.f, 0.f, 0.f};
#pragma unroll
  for (int ks = 0; ks < 2; ++ks) {
    const half8 af = *reinterpret_cast<const half8*>(
        &q16l[(wr * 16 + lcol) * LDH + ks * 32 + loct]);
#pragma unroll
    for (int f = 0; f < 5; ++f) {
      const half8 bf = *reinterpret_cast<const half8*>(
          &kv16[(wc * 80 + f * 16 + lcol) * LDH + ks * 32 + loct]);
      accS[f] =
          __builtin_amdgcn_mfma_f32_16x16x32_f16(af, bf, accS[f], 0, 0, 0);
    }
  }
#pragma unroll
  for (int f = 0; f < 5; ++f) {
    const int slot = wc * 80 + f * 16 + lcol;
    const float vb = vbias[slot];
#pragma unroll
    for (int j = 0; j < 4; ++j) {
      const int row = wr * 16 + (lane >> 4) * 4 + j;
      const bool inband = (slot >= row) && (slot <= row + WIN - 1);
      sS[row * LDS_S + slot] = inband ? (accS[f][j] * scale + vb) : -INFINITY;
    }
  }
  __syncthreads();

  _Float16* vt = kv16;
#pragma unroll
  for (int c = tid; c < SLOTS * 8; c += 256) {
    const int slot = c >> 3, d0 = (c & 7) * 8;
    const int raw = l0 + slot - WIN / 2;
    const int idx = min(max(raw, 0), L_SEQ - 1);
    const half8 vv =
        *reinterpret_cast<const half8*>(&vh[(size_t)idx * HD + d0]);
#pragma unroll
    for (int e = 0; e < 8; ++e) vt[(d0 + e) * LDVT + slot] = vv[e];
  }

  const int r = tid >> 3, wg = tid & 7;
  float pv[20];
  float mloc = -INFINITY;
#pragma unroll
  for (int i = 0; i < 20; ++i) {
    pv[i] = sS[r * LDS_S + wg * 20 + i];
    mloc = fmaxf(mloc, pv[i]);
  }
#pragma unroll
  for (int m = 1; m < 8; m <<= 1) mloc = fmaxf(mloc, __shfl_xor(mloc, m));
  float ssum = 0.f;
#pragma unroll
  for (int i = 0; i < 20; ++i) {
    pv[i] = __expf(pv[i] - mloc);
    ssum += pv[i];
  }
#pragma unroll
  for (int m = 1; m < 8; m <<= 1) ssum += __shfl_xor(ssum, m);
  const float rcp = 1.0f / ssum;
  __syncthreads();

  _Float16* pS = reinterpret_cast<_Float16*>(sS);
#pragma unroll
  for (int i = 0; i < 20; ++i)
    pS[r * (2 * LDS_S) + wg * 20 + i] = (_Float16)(pv[i] * rcp);
  __syncthreads();

  floatx4 accO[2];
  accO[0] = (floatx4){0.f, 0.f, 0.f, 0.f};
  accO[1] = (floatx4){0.f, 0.f, 0.f, 0.f};
#pragma unroll
  for (int ks = 0; ks < 5; ++ks) {
    const half8 ap = *reinterpret_cast<const half8*>(
        &pS[(wr * 16 + lcol) * (2 * LDS_S) + ks * 32 + loct]);
#pragma unroll
    for (int cf = 0; cf < 2; ++cf) {
      const half8 bv = *reinterpret_cast<const half8*>(
          &vt[(wc * 32 + cf * 16 + lcol) * LDVT + ks * 32 + loct]);
      accO[cf] =
          __builtin_amdgcn_mfma_f32_16x16x32_f16(ap, bv, accO[cf], 0, 0, 0);
    }
  }
#pragma unroll
  for (int cf = 0; cf < 2; ++cf)
#pragma unroll
    for (int j = 0; j < 4; ++j) {
      const int row = wr * 16 + (lane >> 4) * 4 + j;
      const int d = wc * 32 + cf * 16 + lcol;
      joined[(size_t)(l0 + row) * D_MODEL + h * HD + d] =
          (_Float16)accO[cf][j];
    }
}

// ---------------------------------------------------------------------------
// CLS attention split-L — fp16 inputs, fp32 accumulation. CSPLIT=32.
// ---------------------------------------------------------------------------
#define CSPLIT 32
#define CROWS (L_SEQ / CSPLIT)  // 64
#define CREC 66

__global__ __launch_bounds__(256) void cls_partial_kernel(
    const _Float16* __restrict__ q16, const _Float16* __restrict__ k16,
    const _Float16* __restrict__ v16, const int* __restrict__ mask,
    float* __restrict__ part) {
  const int h = blockIdx.x;
  const int sp = blockIdx.y;
  const int tid = threadIdx.x;
  const int l0 = sp * CROWS;
  const float scale = 0.036084391824351615f;

  __shared__ float scS[CROWS];
  __shared__ float red[256];
  __shared__ float pvS[4][HD];

  const _Float16* kh = k16 + (size_t)h * L_SEQ * HD;
  const _Float16* vh = v16 + (size_t)h * L_SEQ * HD;

  const int lq = tid >> 4;
  const int dq = tid & 15;
  const half4v q4 =
      *reinterpret_cast<const half4v*>(&q16[(size_t)h * L_SEQ * HD + dq * 4]);
#pragma unroll
  for (int it = 0; it < CROWS / 16; ++it) {
    const int l = l0 + it * 16 + lq;
    const half4v k4 =
        *reinterpret_cast<const half4v*>(&kh[(size_t)l * HD + dq * 4]);
    float p = (float)q4[0] * (float)k4[0] + (float)q4[1] * (float)k4[1] +
              (float)q4[2] * (float)k4[2] + (float)q4[3] * (float)k4[3];
#pragma unroll
    for (int m = 1; m < 16; m <<= 1) p += __shfl_xor(p, m);
    if (dq == 0) scS[it * 16 + lq] = (mask[l] != 0) ? p * scale : -INFINITY;
  }
  __syncthreads();

  red[tid] = (tid < CROWS) ? scS[tid] : -INFINITY;
  __syncthreads();
  for (int off = 128; off > 0; off >>= 1) {
    if (tid < off) red[tid] = fmaxf(red[tid], red[tid + off]);
    __syncthreads();
  }
  const float mx = red[0];
  __syncthreads();

  float e = 0.f;
  if (tid < CROWS) {
    e = (mx == -INFINITY) ? 0.f : __expf(scS[tid] - mx);
    scS[tid] = e;
  }
  red[tid] = e;
  __syncthreads();
  for (int off = 128; off > 0; off >>= 1) {
    if (tid < off) red[tid] += red[tid + off];
    __syncthreads();
  }
  const float lsum = red[0];
  __syncthreads();

  const int lg = tid >> 6;
  const int d = tid & 63;
  float acc = 0.f;
#pragma unroll 8
  for (int it = 0; it < CROWS / 4; ++it) {
    const int ll = lg + it * 4;
    acc += scS[ll] * (float)vh[(size_t)(l0 + ll) * HD + d];
  }
  pvS[lg][d] = acc;
  __syncthreads();

  float* rec = &part[(size_t)(h * CSPLIT + sp) * CREC];
  if (tid == 0) {
    rec[0] = mx;
    rec[1] = lsum;
  }
  if (tid < HD)
    rec[2 + tid] = pvS[0][tid] + pvS[1][tid] + pvS[2][tid] + pvS[3][tid];
}

__global__ __launch_bounds__(64) void cls_combine_kernel(
    const float* __restrict__ part, _Float16* __restrict__ joined) {
  const int h = blockIdx.x;
  const int d = threadIdx.x;

  float gmax = -INFINITY;
#pragma unroll
  for (int sp = 0; sp < CSPLIT; ++sp)
    gmax = fmaxf(gmax, part[(size_t)(h * CSPLIT + sp) * CREC]);

  float total = 0.f, acc = 0.f;
#pragma unroll
  for (int sp = 0; sp < CSPLIT; ++sp) {
    const float* rec = &part[(size_t)(h * CSPLIT + sp) * CREC];
    const float mxi = rec[0];
    const float w = (mxi == -INFINITY) ? 0.f : __expf(mxi - gmax);
    total += w * rec[1];
    acc += w * rec[2 + d];
  }
  joined[(size_t)h * HD + d] = (_Float16)(acc / total);
}

// ---------------------------------------------------------------------------
extern "C" void kernel_launch(void* const* d_in, const int* in_sizes, int n_in,
                              void* d_out, int out_size, void* d_ws,
                              size_t ws_size, hipStream_t stream) {
  const float* emb   = (const float*)d_in[0];
  const int*   mask  = (const int*)d_in[1];
  const float* W_qkv = (const float*)d_in[2];
  const float* b_qkv = (const float*)d_in[3];
  const float* W_o   = (const float*)d_in[4];
  const float* b_o   = (const float*)d_in[5];
  float* out = (float*)d_out;

  _Float16* hp = (_Float16*)d_ws;
  _Float16* A16   = hp;                                      // 2048*768
  _Float16* Wq16T = A16 + (size_t)L_SEQ * D_MODEL;           // 2304*768
  _Float16* Wo16T = Wq16T + (size_t)QKV_N * D_MODEL;         // 768*768
  _Float16* q16   = Wo16T + (size_t)D_MODEL * D_MODEL;       // 12*2048*64
  _Float16* k16   = q16 + (size_t)NHEAD * L_SEQ * HD;
  _Float16* v16   = k16 + (size_t)NHEAD * L_SEQ * HD;
  _Float16* J16   = v16 + (size_t)NHEAD * L_SEQ * HD;        // 2048*768
  float*    part  = (float*)(J16 + (size_t)L_SEQ * D_MODEL); // 12*32*66

  cvt16_kernel<<<(L_SEQ * D_MODEL) / 1024, 256, 0, stream>>>(
      emb, A16, L_SEQ * D_MODEL);
  cvt_transpose16_kernel<<<dim3(QKV_N / 64, D_MODEL / 64), 256, 0, stream>>>(
      W_qkv, Wq16T, D_MODEL, QKV_N);
  cvt_transpose16_kernel<<<dim3(D_MODEL / 64, D_MODEL / 64), 256, 0, stream>>>(
      W_o, Wo16T, D_MODEL, D_MODEL);

  // QKV GEMM + fused RoPE/split epilogue
  gemm16_kernel<64, 128, _Float16, true>
      <<<dim3(QKV_N / 128, L_SEQ / 64), 256, 0, stream>>>(
          A16, Wq16T, b_qkv, (_Float16*)nullptr, q16, k16, v16, L_SEQ, QKV_N,
          D_MODEL);

  cls_partial_kernel<<<dim3(NHEAD, CSPLIT), 256, 0, stream>>>(q16, k16, v16,
                                                              mask, part);

  win_attn_kernel<<<dim3(L_SEQ / TL, NHEAD), 256, 0, stream>>>(q16, k16, v16,
                                                               mask, J16);

  cls_combine_kernel<<<NHEAD, 64, 0, stream>>>(part, J16);

  gemm16_kernel<64, 64, float, false>
      <<<dim3(D_MODEL / 64, L_SEQ / 64), 256, 0, stream>>>(
          J16, Wo16T, b_o, out, (_Float16*)nullptr, (_Float16*)nullptr,
          (_Float16*)nullptr, L_SEQ, D_MODEL, D_MODEL);
}

// Round 10
// 123.841 us; speedup vs baseline: 4.5107x; 1.0563x over previous
//
#include <hip/hip_runtime.h>
#include <hip/hip_bf16.h>
#include <cmath>

#define D_MODEL 768
#define NHEAD 12
#define HD 64
#define L_SEQ 2048
#define WIN 128
#define QKV_N (3 * D_MODEL)

typedef _Float16 half8 __attribute__((ext_vector_type(8)));
typedef _Float16 half4v __attribute__((ext_vector_type(4)));
typedef float floatx4 __attribute__((ext_vector_type(4)));

// ---------------------------------------------------------------------------
// Fused conversions: [0,1536) cvt emb->fp16; [1536,1968) transpose W_qkv;
// [1968,2112) transpose W_o. One launch instead of three.
// ---------------------------------------------------------------------------
#define CVT_A_BLKS 1536                      // 2048*768/4/256
#define CVT_B_BLKS (36 * 12)                 // W_qkv tiles (Cn/64 x R/64)
#define CVT_C_BLKS (12 * 12)                 // W_o tiles

__global__ __launch_bounds__(256) void cvt_fused_kernel(
    const float* __restrict__ emb, _Float16* __restrict__ A16,
    const float* __restrict__ W_qkv, _Float16* __restrict__ Wq16T,
    const float* __restrict__ W_o, _Float16* __restrict__ Wo16T) {
  __shared__ float tile[64][68];
  const int bid = blockIdx.x;
  const int tid = threadIdx.x;

  if (bid < CVT_A_BLKS) {
    const int i = (bid * 256 + tid) * 4;
    const float4 v = *reinterpret_cast<const float4*>(&emb[i]);
    half4v h = {(_Float16)v.x, (_Float16)v.y, (_Float16)v.z, (_Float16)v.w};
    *reinterpret_cast<half4v*>(&A16[i]) = h;
    return;
  }
  const float* In;
  _Float16* Out;
  int R, Cn, bx, by;
  if (bid < CVT_A_BLKS + CVT_B_BLKS) {
    const int b = bid - CVT_A_BLKS;
    In = W_qkv; Out = Wq16T; R = D_MODEL; Cn = QKV_N;
    bx = b % 36; by = b / 36;
  } else {
    const int b = bid - CVT_A_BLKS - CVT_B_BLKS;
    In = W_o; Out = Wo16T; R = D_MODEL; Cn = D_MODEL;
    bx = b % 12; by = b / 12;
  }
  const int r0 = by * 64, c0 = bx * 64;
  const int tr = tid >> 4, tc4 = (tid & 15) * 4;
#pragma unroll
  for (int rr = 0; rr < 4; ++rr) {
    const int r = rr * 16 + tr;
    const float4 v =
        *reinterpret_cast<const float4*>(&In[(size_t)(r0 + r) * Cn + c0 + tc4]);
    tile[r][tc4 + 0] = v.x;
    tile[r][tc4 + 1] = v.y;
    tile[r][tc4 + 2] = v.z;
    tile[r][tc4 + 3] = v.w;
  }
  __syncthreads();
#pragma unroll
  for (int cc = 0; cc < 4; ++cc) {
    const int c = cc * 16 + tr;
    half4v h = {(_Float16)tile[tc4 + 0][c], (_Float16)tile[tc4 + 1][c],
                (_Float16)tile[tc4 + 2][c], (_Float16)tile[tc4 + 3][c]};
    *reinterpret_cast<half4v*>(&Out[(size_t)(c0 + c) * R + r0 + tc4]) = h;
  }
}

// ---------------------------------------------------------------------------
// fp16 MFMA GEMM, reg-staged 2-phase pipeline. ROPE=true (BN=128): fused
// RoPE+split epilogue writing q16/k16/v16 [H][L][64] and v16T [768][L].
// C/D layout (m89-verified): col = lane&15, row = (lane>>4)*4 + j.
// ---------------------------------------------------------------------------
template <int BM, int BN, typename OutT, bool ROPE>
__global__ __launch_bounds__(256) void gemm16_kernel(
    const _Float16* __restrict__ A, const _Float16* __restrict__ BT,
    const float* __restrict__ bias, OutT* __restrict__ C,
    _Float16* __restrict__ q16, _Float16* __restrict__ k16,
    _Float16* __restrict__ v16, _Float16* __restrict__ v16T, int M, int N,
    int K) {
  constexpr int LDK = 40;
  constexpr int MF = BM / 32;
  constexpr int NF = BN / 32;
  constexpr int CA = BM * 4 / 256;
  constexpr int CB = BN * 4 / 256;

  __shared__ __align__(16) _Float16 At[BM * LDK];
  __shared__ __align__(16) _Float16 Bt[BN * LDK];

  const int tid = threadIdx.x;
  const int row0 = blockIdx.y * BM;
  const int col0 = blockIdx.x * BN;
  const int wv = tid >> 6;
  const int lane = tid & 63;
  const int wr = wv >> 1;
  const int wc = wv & 1;
  const int lrow = lane & 15;
  const int lk = lane >> 4;

  floatx4 acc[MF][NF];
#pragma unroll
  for (int m = 0; m < MF; ++m)
#pragma unroll
    for (int n = 0; n < NF; ++n) acc[m][n] = (floatx4){0.f, 0.f, 0.f, 0.f};

  half8 aR[CA], bR[CB];
  const int nt = K / 32;

#pragma unroll
  for (int i = 0; i < CA; ++i) {
    const int c = tid + i * 256, r = c >> 2, seg = c & 3;
    aR[i] = *reinterpret_cast<const half8*>(&A[(size_t)(row0 + r) * K + seg * 8]);
  }
#pragma unroll
  for (int i = 0; i < CB; ++i) {
    const int c = tid + i * 256, r = c >> 2, seg = c & 3;
    bR[i] =
        *reinterpret_cast<const half8*>(&BT[(size_t)(col0 + r) * K + seg * 8]);
  }

  for (int t = 0; t < nt; ++t) {
    if (t) __syncthreads();
#pragma unroll
    for (int i = 0; i < CA; ++i) {
      const int c = tid + i * 256, r = c >> 2, seg = c & 3;
      *reinterpret_cast<half8*>(&At[r * LDK + seg * 8]) = aR[i];
    }
#pragma unroll
    for (int i = 0; i < CB; ++i) {
      const int c = tid + i * 256, r = c >> 2, seg = c & 3;
      *reinterpret_cast<half8*>(&Bt[r * LDK + seg * 8]) = bR[i];
    }
    __syncthreads();

    if (t + 1 < nt) {
      const int k0 = (t + 1) * 32;
#pragma unroll
      for (int i = 0; i < CA; ++i) {
        const int c = tid + i * 256, r = c >> 2, seg = c & 3;
        aR[i] = *reinterpret_cast<const half8*>(
            &A[(size_t)(row0 + r) * K + k0 + seg * 8]);
      }
#pragma unroll
      for (int i = 0; i < CB; ++i) {
        const int c = tid + i * 256, r = c >> 2, seg = c & 3;
        bR[i] = *reinterpret_cast<const half8*>(
            &BT[(size_t)(col0 + r) * K + k0 + seg * 8]);
      }
    }

    half8 af[MF], bf[NF];
#pragma unroll
    for (int m = 0; m < MF; ++m)
      af[m] = *reinterpret_cast<const half8*>(
          &At[(wr * (BM / 2) + m * 16 + lrow) * LDK + lk * 8]);
#pragma unroll
    for (int n = 0; n < NF; ++n)
      bf[n] = *reinterpret_cast<const half8*>(
          &Bt[(wc * (BN / 2) + n * 16 + lrow) * LDK + lk * 8]);
#pragma unroll
    for (int m = 0; m < MF; ++m)
#pragma unroll
      for (int n = 0; n < NF; ++n)
        acc[m][n] = __builtin_amdgcn_mfma_f32_16x16x32_f16(af[m], bf[n],
                                                           acc[m][n], 0, 0, 0);
  }

  if constexpr (!ROPE) {
#pragma unroll
    for (int m = 0; m < MF; ++m)
#pragma unroll
      for (int n = 0; n < NF; ++n) {
        const int col = col0 + wc * (BN / 2) + n * 16 + lrow;
        const float bb = bias[col];
#pragma unroll
        for (int j = 0; j < 4; ++j) {
          const int row = row0 + wr * (BM / 2) + m * 16 + lk * 4 + j;
          C[(size_t)row * N + col] = (OutT)(acc[m][n][j] + bb);
        }
      }
  } else {
    const int part = col0 / D_MODEL;             // 0=q 1=k 2=v
    const int h = ((col0 % D_MODEL) >> 6) + wc;  // head
    _Float16* dst = (part == 0) ? q16 : (part == 1) ? k16 : v16;
    float bb[4];
#pragma unroll
    for (int n = 0; n < 4; ++n) bb[n] = bias[col0 + wc * 64 + n * 16 + lrow];
    const float inv0 = exp2f(-0.4152410118609203f * (float)lrow);
    const float inv1 = inv0 * 0.01f;  // *10000^(-32/64)
#pragma unroll
    for (int m = 0; m < MF; ++m) {
#pragma unroll
      for (int j = 0; j < 4; ++j) {
        const int l = row0 + wr * (BM / 2) + m * 16 + lk * 4 + j;
        float val[4];
#pragma unroll
        for (int n = 0; n < 4; ++n) val[n] = acc[m][n][j] + bb[n];
        float o[4];
        if (part < 2) {
          float sn0, cs0, sn1, cs1;
          __sincosf((float)l * inv0, &sn0, &cs0);
          __sincosf((float)l * inv1, &sn1, &cs1);
          o[0] = val[0] * cs0 - val[2] * sn0;
          o[1] = val[1] * cs1 - val[3] * sn1;
          o[2] = val[0] * sn0 + val[2] * cs0;
          o[3] = val[1] * sn1 + val[3] * cs1;
        } else {
          o[0] = val[0]; o[1] = val[1]; o[2] = val[2]; o[3] = val[3];
        }
        const size_t base = ((size_t)h * L_SEQ + l) * HD + lrow;
#pragma unroll
        for (int n = 0; n < 4; ++n) dst[base + n * 16] = (_Float16)o[n];
      }
      if (part == 2) {
        // transposed V: contiguous along l (half4 per (m,n))
        const int lb = row0 + wr * (BM / 2) + m * 16 + lk * 4;
#pragma unroll
        for (int n = 0; n < 4; ++n) {
          const int col = h * HD + n * 16 + lrow;  // 0..767
          half4v hv = {(_Float16)(acc[m][n][0] + bb[n]),
                       (_Float16)(acc[m][n][1] + bb[n]),
                       (_Float16)(acc[m][n][2] + bb[n]),
                       (_Float16)(acc[m][n][3] + bb[n])};
          *reinterpret_cast<half4v*>(&v16T[(size_t)col * L_SEQ + lb]) = hv;
        }
      }
    }
  }
}

// ---------------------------------------------------------------------------
// Attention megakernel: grid ((L/TL)+CSPLIT, NHEAD).
//  blockIdx.x <  64      : window attention (MFMA), as R7-validated, with
//                          clamp-free staging (P=0 kills OOB garbage) and
//                          V^T staged coalesced from v16T (no LDS scatter).
//  blockIdx.x >= 64      : CLS split-L partial (sp = blockIdx.x - 64).
// ---------------------------------------------------------------------------
#define TL 32
#define SLOTS 160
#define LDH 72
#define LDS_S 168
#define LDVT 168
#define CSPLIT 32
#define CROWS (L_SEQ / CSPLIT)  // 64
#define CREC 66

__global__ __launch_bounds__(256) void attn_mega_kernel(
    const _Float16* __restrict__ q16, const _Float16* __restrict__ k16,
    const _Float16* __restrict__ v16, const _Float16* __restrict__ v16T,
    const int* __restrict__ mask, _Float16* __restrict__ joined,
    float* __restrict__ part) {
  const int h = blockIdx.y;
  const int tid = threadIdx.x;
  const float scale = 0.036084391824351615f;  // 1/sqrt(768)

  __shared__ __align__(16) _Float16 kv16[SLOTS * LDH];
  __shared__ __align__(16) float sS[TL * LDS_S];
  __shared__ __align__(16) _Float16 q16l[TL * LDH];
  __shared__ float vbias[SLOTS];

  if (blockIdx.x < (L_SEQ / TL)) {
    // ================= window attention =================
    const int l0 = blockIdx.x * TL;
    const _Float16* kh = k16 + (size_t)h * L_SEQ * HD;
    const _Float16* qh = q16 + (size_t)h * L_SEQ * HD;

    {
      const int row = tid >> 3, oct = (tid & 7) * 8;
      *reinterpret_cast<half8*>(&q16l[row * LDH + oct]) =
          *reinterpret_cast<const half8*>(&qh[(size_t)(l0 + row) * HD + oct]);
    }
    // K: clamp-free (OOB slots are masked to P=0; ws bytes are finite fp16)
    const _Float16* kwin = kh + (size_t)(l0 - WIN / 2) * HD;
#pragma unroll
    for (int c = tid; c < SLOTS * 8; c += 256) {
      const int slot = c >> 3, oct = (c & 7) * 8;
      *reinterpret_cast<half8*>(&kv16[slot * LDH + oct]) =
          *reinterpret_cast<const half8*>(&kwin[(size_t)slot * HD + oct]);
    }
    if (tid < SLOTS) {
      const int raw = l0 + tid - WIN / 2;
      const int idx = min(max(raw, 0), L_SEQ - 1);
      vbias[tid] =
          ((raw >= 0) && (raw < L_SEQ) && (mask[idx] != 0)) ? 0.f : -INFINITY;
    }
    __syncthreads();

    const int wv = tid >> 6, lane = tid & 63;
    const int wr = wv >> 1, wc = wv & 1;
    const int lcol = lane & 15, loct = (lane >> 4) * 8;

    floatx4 accS[5];
#pragma unroll
    for (int f = 0; f < 5; ++f) accS[f] = (floatx4){0.f, 0.f, 0.f, 0.f};
#pragma unroll
    for (int ks = 0; ks < 2; ++ks) {
      const half8 af = *reinterpret_cast<const half8*>(
          &q16l[(wr * 16 + lcol) * LDH + ks * 32 + loct]);
#pragma unroll
      for (int f = 0; f < 5; ++f) {
        const half8 bf = *reinterpret_cast<const half8*>(
            &kv16[(wc * 80 + f * 16 + lcol) * LDH + ks * 32 + loct]);
        accS[f] =
            __builtin_amdgcn_mfma_f32_16x16x32_f16(af, bf, accS[f], 0, 0, 0);
      }
    }
#pragma unroll
    for (int f = 0; f < 5; ++f) {
      const int slot = wc * 80 + f * 16 + lcol;
      const float vb = vbias[slot];
#pragma unroll
      for (int j = 0; j < 4; ++j) {
        const int row = wr * 16 + (lane >> 4) * 4 + j;
        const bool inband = (slot >= row) && (slot <= row + WIN - 1);
        sS[row * LDS_S + slot] = inband ? (accS[f][j] * scale + vb) : -INFINITY;
      }
    }
    __syncthreads();

    // V^T staged coalesced from v16T (clamp-free)
    _Float16* vt = kv16;
    const _Float16* vtg =
        v16T + (size_t)h * HD * L_SEQ + (l0 - WIN / 2);
#pragma unroll
    for (int c = tid; c < HD * 20; c += 256) {
      const int d = c / 20, seg = c % 20;
      *reinterpret_cast<half8*>(&vt[d * LDVT + seg * 8]) =
          *reinterpret_cast<const half8*>(&vtg[(size_t)d * L_SEQ + seg * 8]);
    }

    const int r = tid >> 3, wg = tid & 7;
    float pv[20];
    float mloc = -INFINITY;
#pragma unroll
    for (int i = 0; i < 20; ++i) {
      pv[i] = sS[r * LDS_S + wg * 20 + i];
      mloc = fmaxf(mloc, pv[i]);
    }
#pragma unroll
    for (int m = 1; m < 8; m <<= 1) mloc = fmaxf(mloc, __shfl_xor(mloc, m));
    float ssum = 0.f;
#pragma unroll
    for (int i = 0; i < 20; ++i) {
      pv[i] = __expf(pv[i] - mloc);
      ssum += pv[i];
    }
#pragma unroll
    for (int m = 1; m < 8; m <<= 1) ssum += __shfl_xor(ssum, m);
    const float rcp = 1.0f / ssum;
    __syncthreads();

    _Float16* pS = reinterpret_cast<_Float16*>(sS);
#pragma unroll
    for (int i = 0; i < 20; ++i)
      pS[r * (2 * LDS_S) + wg * 20 + i] = (_Float16)(pv[i] * rcp);
    __syncthreads();

    floatx4 accO[2];
    accO[0] = (floatx4){0.f, 0.f, 0.f, 0.f};
    accO[1] = (floatx4){0.f, 0.f, 0.f, 0.f};
#pragma unroll
    for (int ks = 0; ks < 5; ++ks) {
      const half8 ap = *reinterpret_cast<const half8*>(
          &pS[(wr * 16 + lcol) * (2 * LDS_S) + ks * 32 + loct]);
#pragma unroll
      for (int cf = 0; cf < 2; ++cf) {
        const half8 bv = *reinterpret_cast<const half8*>(
            &vt[(wc * 32 + cf * 16 + lcol) * LDVT + ks * 32 + loct]);
        accO[cf] =
            __builtin_amdgcn_mfma_f32_16x16x32_f16(ap, bv, accO[cf], 0, 0, 0);
      }
    }
#pragma unroll
    for (int cf = 0; cf < 2; ++cf)
#pragma unroll
      for (int j = 0; j < 4; ++j) {
        const int row = wr * 16 + (lane >> 4) * 4 + j;
        const int d = wc * 32 + cf * 16 + lcol;
        joined[(size_t)(l0 + row) * D_MODEL + h * HD + d] =
            (_Float16)accO[cf][j];
      }
  } else {
    // ================= CLS partial (split-L) =================
    const int sp = blockIdx.x - (L_SEQ / TL);
    const int l0 = sp * CROWS;
    float* scS = sS;           // reuse LDS
    float* red = sS + CROWS;   // 256 floats
    float* pvS = sS + CROWS + 256;  // 4*64 floats

    const _Float16* kh = k16 + (size_t)h * L_SEQ * HD;
    const _Float16* vh = v16 + (size_t)h * L_SEQ * HD;

    const int lq = tid >> 4;
    const int dq = tid & 15;
    const half4v q4 =
        *reinterpret_cast<const half4v*>(&q16[(size_t)h * L_SEQ * HD + dq * 4]);
#pragma unroll
    for (int it = 0; it < CROWS / 16; ++it) {
      const int l = l0 + it * 16 + lq;
      const half4v k4 =
          *reinterpret_cast<const half4v*>(&kh[(size_t)l * HD + dq * 4]);
      float p = (float)q4[0] * (float)k4[0] + (float)q4[1] * (float)k4[1] +
                (float)q4[2] * (float)k4[2] + (float)q4[3] * (float)k4[3];
#pragma unroll
      for (int m = 1; m < 16; m <<= 1) p += __shfl_xor(p, m);
      if (dq == 0) scS[it * 16 + lq] = (mask[l] != 0) ? p * scale : -INFINITY;
    }
    __syncthreads();

    red[tid] = (tid < CROWS) ? scS[tid] : -INFINITY;
    __syncthreads();
    for (int off = 128; off > 0; off >>= 1) {
      if (tid < off) red[tid] = fmaxf(red[tid], red[tid + off]);
      __syncthreads();
    }
    const float mx = red[0];
    __syncthreads();

    float e = 0.f;
    if (tid < CROWS) {
      e = (mx == -INFINITY) ? 0.f : __expf(scS[tid] - mx);
      scS[tid] = e;
    }
    red[tid] = e;
    __syncthreads();
    for (int off = 128; off > 0; off >>= 1) {
      if (tid < off) red[tid] += red[tid + off];
      __syncthreads();
    }
    const float lsum = red[0];
    __syncthreads();

    const int lg = tid >> 6;
    const int d = tid & 63;
    float acc = 0.f;
#pragma unroll 8
    for (int it = 0; it < CROWS / 4; ++it) {
      const int ll = lg + it * 4;
      acc += scS[ll] * (float)vh[(size_t)(l0 + ll) * HD + d];
    }
    pvS[lg * HD + d] = acc;
    __syncthreads();

    float* rec = &part[(size_t)(h * CSPLIT + sp) * CREC];
    if (tid == 0) {
      rec[0] = mx;
      rec[1] = lsum;
    }
    if (tid < HD)
      rec[2 + tid] =
          pvS[0 * HD + tid] + pvS[1 * HD + tid] + pvS[2 * HD + tid] +
          pvS[3 * HD + tid];
  }
}

__global__ __launch_bounds__(64) void cls_combine_kernel(
    const float* __restrict__ part, _Float16* __restrict__ joined) {
  const int h = blockIdx.x;
  const int d = threadIdx.x;

  float gmax = -INFINITY;
#pragma unroll
  for (int sp = 0; sp < CSPLIT; ++sp)
    gmax = fmaxf(gmax, part[(size_t)(h * CSPLIT + sp) * CREC]);

  float total = 0.f, acc = 0.f;
#pragma unroll
  for (int sp = 0; sp < CSPLIT; ++sp) {
    const float* rec = &part[(size_t)(h * CSPLIT + sp) * CREC];
    const float mxi = rec[0];
    const float w = (mxi == -INFINITY) ? 0.f : __expf(mxi - gmax);
    total += w * rec[1];
    acc += w * rec[2 + d];
  }
  joined[(size_t)h * HD + d] = (_Float16)(acc / total);
}

// ---------------------------------------------------------------------------
extern "C" void kernel_launch(void* const* d_in, const int* in_sizes, int n_in,
                              void* d_out, int out_size, void* d_ws,
                              size_t ws_size, hipStream_t stream) {
  const float* emb   = (const float*)d_in[0];
  const int*   mask  = (const int*)d_in[1];
  const float* W_qkv = (const float*)d_in[2];
  const float* b_qkv = (const float*)d_in[3];
  const float* W_o   = (const float*)d_in[4];
  const float* b_o   = (const float*)d_in[5];
  float* out = (float*)d_out;

  _Float16* hp = (_Float16*)d_ws;
  _Float16* A16   = hp;                                      // 2048*768
  _Float16* Wq16T = A16 + (size_t)L_SEQ * D_MODEL;           // 2304*768
  _Float16* Wo16T = Wq16T + (size_t)QKV_N * D_MODEL;         // 768*768
  _Float16* q16   = Wo16T + (size_t)D_MODEL * D_MODEL;       // 12*2048*64
  _Float16* k16   = q16 + (size_t)NHEAD * L_SEQ * HD;
  _Float16* v16   = k16 + (size_t)NHEAD * L_SEQ * HD;
  _Float16* v16T  = v16 + (size_t)NHEAD * L_SEQ * HD;        // [768][2048]
  _Float16* J16   = v16T + (size_t)D_MODEL * L_SEQ;          // 2048*768
  float*    part  = (float*)(J16 + (size_t)L_SEQ * D_MODEL); // 12*32*66

  cvt_fused_kernel<<<CVT_A_BLKS + CVT_B_BLKS + CVT_C_BLKS, 256, 0, stream>>>(
      emb, A16, W_qkv, Wq16T, W_o, Wo16T);

  gemm16_kernel<64, 128, _Float16, true>
      <<<dim3(QKV_N / 128, L_SEQ / 64), 256, 0, stream>>>(
          A16, Wq16T, b_qkv, (_Float16*)nullptr, q16, k16, v16, v16T, L_SEQ,
          QKV_N, D_MODEL);

  attn_mega_kernel<<<dim3(L_SEQ / TL + CSPLIT, NHEAD), 256, 0, stream>>>(
      q16, k16, v16, v16T, mask, J16, part);

  cls_combine_kernel<<<NHEAD, 64, 0, stream>>>(part, J16);

  gemm16_kernel<64, 64, float, false>
      <<<dim3(D_MODEL / 64, L_SEQ / 64), 256, 0, stream>>>(
          J16, Wo16T, b_o, out, (_Float16*)nullptr, (_Float16*)nullptr,
          (_Float16*)nullptr, (_Float16*)nullptr, L_SEQ, D_MODEL, D_MODEL);
}